// Round 1
// baseline (457.098 us; speedup 1.0000x reference)
//
#include <hip/hip_runtime.h>
#include <hip/hip_bf16.h>
#include <cstdint>
#include <cstddef>

#define L_TOT 16384
#define B_SZ 2
#define NROW (B_SZ * L_TOT)
#define CHUNK 64
#define NCH (L_TOT / CHUNK)

static constexpr size_t SLOT_XD  = (size_t)NROW * 64;        // xd / dt per-dir
static constexpr size_t SLOT_BC  = (size_t)NROW * 16;        // B,C per-dir
static constexpr size_t SLOT_SDT = (size_t)B_SZ * NCH * 64;  // sum(dt) per chunk
static constexpr size_t SLOT_HC  = (size_t)B_SZ * NCH * 64 * 8; // chunk-local h / h_start

// scan-position s -> original sequence index l (also the scatter index; tau is
// its own inverse composed with sigma: verified sigma^{-1} == tau for H==W).
__device__ __forceinline__ int tau_map(int dir, int s) {
  int j = (dir & 1) ? (L_TOT - 1 - s) : s;
  if (dir >= 2) j = ((j & 127) << 7) | (j >> 7);   // transpose of 128x128
  return j;
}
__device__ __forceinline__ float silu_f(float x) { return x / (1.f + __expf(-x)); }
__device__ __forceinline__ float softplus_f(float x) { return (x > 20.f) ? x : log1pf(__expf(x)); }

// ---------------- A: LayerNorm + in_proj (one 64-wide j-half per block) ----------------
__global__ void k_ln_inproj(const float* __restrict__ inp, const float* __restrict__ lng,
                            const float* __restrict__ lnb, const float* __restrict__ W,
                            float* __restrict__ xout, float* __restrict__ zout) {
  __shared__ float sm[64 * 65];
  const int t  = threadIdx.x;          // 0..63 = l within tile
  const int jh = blockIdx.y;           // 0 -> x half, 1 -> z half
  const int blk = blockIdx.x;          // 0..511
  const int b  = blk >> 8;
  const int l0 = (blk & 255) << 6;
  const float* ip = inp + (size_t)b * 64 * L_TOT + l0;
  for (int c = 0; c < 64; ++c)                       // coalesced along l
    sm[c * 65 + t] = ip[(size_t)c * L_TOT + t];
  __syncthreads();
  float xr[64];
  float m = 0.f;
#pragma unroll
  for (int c = 0; c < 64; ++c) { float v = sm[c * 65 + t]; xr[c] = v; m += v; }
  m *= 0.015625f;
  float var = 0.f;
#pragma unroll
  for (int c = 0; c < 64; ++c) { float dv = xr[c] - m; var += dv * dv; }
  var *= 0.015625f;
  const float rstd = rsqrtf(var + 1e-5f);
#pragma unroll
  for (int c = 0; c < 64; ++c) xr[c] = (xr[c] - m) * rstd * lng[c] + lnb[c];
  __syncthreads();
  const float* Wp = W + (size_t)(jh << 6) * 64;      // rows jh*64 .. jh*64+63
#pragma unroll 1
  for (int j = 0; j < 64; ++j) {
    float acc = 0.f;
#pragma unroll
    for (int c = 0; c < 64; ++c) acc += xr[c] * Wp[j * 64 + c];  // uniform s_loads
    sm[t * 65 + j] = acc;
  }
  __syncthreads();
  float* op = (jh ? zout : xout) + ((size_t)b * L_TOT + l0) * 64;
#pragma unroll 1
  for (int r = 0; r < 64; ++r)
    op[(size_t)r * 64 + t] = sm[r * 65 + t];         // coalesced store
}

// ---------------- B: gather + depthwise causal conv(4) + SiLU ----------------
__global__ void k_conv(const float* __restrict__ xbuf, const float* __restrict__ cw,
                       const float* __restrict__ cb, float* __restrict__ xd, int dir) {
  const int t = threadIdx.x;           // 256 = 4 waves, wave per sequence position
  const int lane = t & 63;             // channel
  const int w = t >> 6;
  const int sg = blockIdx.x * 4 + w;   // 0 .. NROW-1
  const int b = sg >> 14;
  const int s = sg & (L_TOT - 1);
  float wk[4];
#pragma unroll
  for (int k = 0; k < 4; ++k) wk[k] = cw[(dir * 64 + lane) * 4 + k];
  float acc = cb[dir * 64 + lane];
#pragma unroll
  for (int k = 0; k < 4; ++k) {
    int j = s - 3 + k;
    if (j >= 0) {
      int l = tau_map(dir, j);
      acc += wk[k] * xbuf[((size_t)b * L_TOT + l) * 64 + lane];
    }
  }
  xd[((size_t)b * L_TOT + s) * 64 + lane] = silu_f(acc);
}

// ---------------- C: xproj (20 outs) + dtproj (64 outs) + softplus ----------------
__global__ void k_proj(const float* __restrict__ xd, const float* __restrict__ xpw,
                       const float* __restrict__ dtw, const float* __restrict__ dtbias,
                       float* __restrict__ dtout, float* __restrict__ bcout, int dir) {
  __shared__ float xt[64 * 65];
  __shared__ float dbl[64 * 20];
  const int t = threadIdx.x;           // 256
  const int blk = blockIdx.x;          // 512
  const int b = blk >> 8;
  const int s0 = (blk & 255) << 6;
  const float* xp = xd + ((size_t)b * L_TOT + s0) * 64;
  {
    const int c = t & 63;
    const int r0 = t >> 6;
#pragma unroll 1
    for (int rr = 0; rr < 16; ++rr) {
      int r = rr * 4 + r0;
      xt[r * 65 + c] = xp[(size_t)r * 64 + c];
    }
  }
  __syncthreads();
  {
    const int g = t >> 6;              // uniform per wave -> weight loads are scalar
    const int srow = t & 63;
    float acc[5] = {0.f, 0.f, 0.f, 0.f, 0.f};
    const float* wp = xpw + ((size_t)dir * 20 + g * 5) * 64;
#pragma unroll 1
    for (int c = 0; c < 64; ++c) {
      float xv = xt[srow * 65 + c];
#pragma unroll
      for (int jj = 0; jj < 5; ++jj) acc[jj] += xv * wp[jj * 64 + c];
    }
#pragma unroll
    for (int jj = 0; jj < 5; ++jj) dbl[srow * 20 + g * 5 + jj] = acc[jj];
  }
  __syncthreads();
  {  // dt = softplus(dbl[:, :4] @ dtw.T + bias) : 64 rows x 64 ch
    const int c = t & 63;
    float wdt[4];
#pragma unroll
    for (int r = 0; r < 4; ++r) wdt[r] = dtw[((size_t)dir * 64 + c) * 4 + r];
    const float bia = dtbias[dir * 64 + c];
#pragma unroll 1
    for (int rep = 0; rep < 16; ++rep) {
      int srow = rep * 4 + (t >> 6);
      float acc = bia;
#pragma unroll
      for (int r = 0; r < 4; ++r) acc += wdt[r] * dbl[srow * 20 + r];
      dtout[((size_t)b * L_TOT + s0 + srow) * 64 + c] = softplus_f(acc);
    }
  }
  {  // B,C: 64 rows x 16
#pragma unroll 1
    for (int rep = 0; rep < 4; ++rep) {
      int idx = rep * 256 + t;
      int srow = idx >> 4;
      int j = idx & 15;
      bcout[((size_t)b * L_TOT + s0 + srow) * 16 + j] = dbl[srow * 20 + 4 + j];
    }
  }
}

// ---------------- S1: chunk-local scan (h=0 start), store h_end + sum(dt) ----------------
__global__ void k_scan1(const float* __restrict__ dtb, const float* __restrict__ xdb,
                        const float* __restrict__ bcb, const float* __restrict__ alog,
                        float* __restrict__ hcb, float* __restrict__ sdtb, int dir_base) {
  const int d = threadIdx.x;           // 64 channels
  const int ch = blockIdx.x;           // NCH chunks
  const int slot = blockIdx.y;
  const int dir = dir_base + slot;
  const int b = blockIdx.z;
  float a[8];
#pragma unroll
  for (int n = 0; n < 8; ++n) a[n] = -__expf(alog[((size_t)dir * 64 + d) * 8 + n]);
  const float* dtp = dtb + (size_t)slot * SLOT_XD + ((size_t)b * L_TOT + ch * CHUNK) * 64;
  const float* xdp = xdb + (size_t)slot * SLOT_XD + ((size_t)b * L_TOT + ch * CHUNK) * 64;
  const float* bcp = bcb + (size_t)slot * SLOT_BC + ((size_t)b * L_TOT + ch * CHUNK) * 16;
  float h[8] = {0,0,0,0,0,0,0,0};
  float sdt = 0.f;
#pragma unroll 1
  for (int s = 0; s < CHUNK; ++s) {
    float dt = dtp[s * 64 + d];
    float u  = xdp[s * 64 + d];
    sdt += dt;
    float du = dt * u;
#pragma unroll
    for (int n = 0; n < 8; ++n)
      h[n] = __expf(dt * a[n]) * h[n] + du * bcp[s * 16 + n];
  }
  sdtb[(size_t)slot * SLOT_SDT + ((size_t)b * NCH + ch) * 64 + d] = sdt;
  float* hp = hcb + (size_t)slot * SLOT_HC + (((size_t)b * NCH + ch) * 64 + d) * 8;
#pragma unroll
  for (int n = 0; n < 8; ++n) hp[n] = h[n];
}

// ---------------- S2: stitch chunks (prod exp(dt*A) == exp(A*sum dt)) ----------------
__global__ void k_scan2(const float* __restrict__ hcb, const float* __restrict__ sdtb,
                        const float* __restrict__ alog, float* __restrict__ hsb, int dir_base) {
  const int d = threadIdx.x;
  const int slot = blockIdx.y;
  const int dir = dir_base + slot;
  const int b = blockIdx.z;
  float a[8];
#pragma unroll
  for (int n = 0; n < 8; ++n) a[n] = -__expf(alog[((size_t)dir * 64 + d) * 8 + n]);
  float h[8] = {0,0,0,0,0,0,0,0};
  const float* hc0 = hcb + (size_t)slot * SLOT_HC + (size_t)b * NCH * 512;
  const float* sd0 = sdtb + (size_t)slot * SLOT_SDT + (size_t)b * NCH * 64;
  float* hs0 = hsb + (size_t)slot * SLOT_HC + (size_t)b * NCH * 512;
#pragma unroll 1
  for (int c = 0; c < NCH; ++c) {
    float* hs = hs0 + ((size_t)c * 64 + d) * 8;
#pragma unroll
    for (int n = 0; n < 8; ++n) hs[n] = h[n];
    float sdt = sd0[(size_t)c * 64 + d];
    const float* hp = hc0 + ((size_t)c * 64 + d) * 8;
#pragma unroll
    for (int n = 0; n < 8; ++n) h[n] = __expf(a[n] * sdt) * h[n] + hp[n];
  }
}

// ---------------- S3: final scan with h_start, y = C.h + u*D, bijective scatter-add ----------------
__global__ void k_scan3(const float* __restrict__ dtp0, const float* __restrict__ xdp0,
                        const float* __restrict__ bcp0, const float* __restrict__ hsp0,
                        const float* __restrict__ alog, const float* __restrict__ dsk,
                        float* __restrict__ ysum, int dir) {
  const int d = threadIdx.x;
  const int ch = blockIdx.x;
  const int b = blockIdx.z;
  float a[8];
#pragma unroll
  for (int n = 0; n < 8; ++n) a[n] = -__expf(alog[((size_t)dir * 64 + d) * 8 + n]);
  const float Dv = dsk[dir * 64 + d];
  const float* dtp = dtp0 + ((size_t)b * L_TOT + ch * CHUNK) * 64;
  const float* xdp = xdp0 + ((size_t)b * L_TOT + ch * CHUNK) * 64;
  const float* bcp = bcp0 + ((size_t)b * L_TOT + ch * CHUNK) * 16;
  const float* hsp = hsp0 + (((size_t)b * NCH + ch) * 64 + d) * 8;
  float h[8];
#pragma unroll
  for (int n = 0; n < 8; ++n) h[n] = hsp[n];
  const int sbase = ch * CHUNK;
#pragma unroll 1
  for (int s = 0; s < CHUNK; ++s) {
    float dt = dtp[s * 64 + d];
    float u  = xdp[s * 64 + d];
    float du = dt * u;
    float y = u * Dv;
#pragma unroll
    for (int n = 0; n < 8; ++n) {
      h[n] = __expf(dt * a[n]) * h[n] + du * bcp[s * 16 + n];
      y += bcp[s * 16 + 8 + n] * h[n];
    }
    int l = tau_map(dir, sbase + s);
    float* yp = ysum + ((size_t)b * L_TOT + l) * 64 + d;
    *yp += y;   // bijective within a dir; dirs serialized on the stream
  }
}

// ---------------- F: /4 + LN + *silu(z) + out_proj + residual ----------------
__global__ void k_final(const float* __restrict__ ysum, const float* __restrict__ zbuf,
                        const float* __restrict__ ong, const float* __restrict__ onb,
                        const float* __restrict__ OW, const float* __restrict__ inp,
                        float* __restrict__ out) {
  __shared__ float ty[64 * 65];
  __shared__ float tz[64 * 65];
  const int t = threadIdx.x;           // 64
  const int jh = blockIdx.y;           // output-channel half (32 each)
  const int blk = blockIdx.x;
  const int b = blk >> 8;
  const int l0 = (blk & 255) << 6;
  const float* yp = ysum + ((size_t)b * L_TOT + l0) * 64;
  const float* zp = zbuf + ((size_t)b * L_TOT + l0) * 64;
#pragma unroll 1
  for (int r = 0; r < 64; ++r) {
    ty[r * 65 + t] = yp[(size_t)r * 64 + t];
    tz[r * 65 + t] = zp[(size_t)r * 64 + t];
  }
  __syncthreads();
  float yr[64];
  float m = 0.f;
#pragma unroll
  for (int c = 0; c < 64; ++c) { float v = ty[t * 65 + c] * 0.25f; yr[c] = v; m += v; }
  m *= 0.015625f;
  float var = 0.f;
#pragma unroll
  for (int c = 0; c < 64; ++c) { float dv = yr[c] - m; var += dv * dv; }
  var *= 0.015625f;
  const float rstd = rsqrtf(var + 1e-5f);
#pragma unroll
  for (int c = 0; c < 64; ++c) {
    float yv = (yr[c] - m) * rstd * ong[c] + onb[c];
    float zz = tz[t * 65 + c];
    yr[c] = yv * silu_f(zz);
  }
  const int j0 = jh << 5;
#pragma unroll 1
  for (int j = j0; j < j0 + 32; ++j) {
    float acc = 0.f;
#pragma unroll
    for (int c = 0; c < 64; ++c) acc += yr[c] * OW[j * 64 + c];
    size_t o = ((size_t)b * 64 + j) * L_TOT + l0 + t;
    out[o] = acc + inp[o];     // coalesced along l
  }
}

extern "C" void kernel_launch(void* const* d_in, const int* in_sizes, int n_in,
                              void* d_out, int out_size, void* d_ws, size_t ws_size,
                              hipStream_t stream) {
  const float* inp    = (const float*)d_in[0];
  const float* lng    = (const float*)d_in[1];
  const float* lnb    = (const float*)d_in[2];
  const float* ipw    = (const float*)d_in[3];
  const float* cw     = (const float*)d_in[4];
  const float* cb     = (const float*)d_in[5];
  const float* xpw    = (const float*)d_in[6];
  const float* dtw    = (const float*)d_in[7];
  const float* dtbias = (const float*)d_in[8];
  const float* alog   = (const float*)d_in[9];
  const float* dsk    = (const float*)d_in[10];
  const float* ong    = (const float*)d_in[11];
  const float* onb    = (const float*)d_in[12];
  const float* opw    = (const float*)d_in[13];
  float* out = (float*)d_out;
  float* ws = (float*)d_ws;

  const size_t per_slot = SLOT_XD * 2 + SLOT_BC + SLOT_SDT + SLOT_HC * 2;
  const size_t fixed = (size_t)NROW * 64 * 3;   // x, z, ysum
  const int nslot = (ws_size >= (fixed + 4 * per_slot) * sizeof(float)) ? 4 : 1;

  size_t off = 0;
  float* xbuf   = ws + off; off += (size_t)NROW * 64;
  float* zbuf   = ws + off; off += (size_t)NROW * 64;
  float* ysum   = ws + off; off += (size_t)NROW * 64;
  float* xd     = ws + off; off += (size_t)nslot * SLOT_XD;
  float* dtb    = ws + off; off += (size_t)nslot * SLOT_XD;
  float* bc     = ws + off; off += (size_t)nslot * SLOT_BC;
  float* sdt    = ws + off; off += (size_t)nslot * SLOT_SDT;
  float* hc     = ws + off; off += (size_t)nslot * SLOT_HC;
  float* hstart = ws + off; off += (size_t)nslot * SLOT_HC;

  hipMemsetAsync(ysum, 0, (size_t)NROW * 64 * sizeof(float), stream);
  k_ln_inproj<<<dim3(512, 2), 64, 0, stream>>>(inp, lng, lnb, ipw, xbuf, zbuf);

  if (nslot == 4) {
    for (int d2 = 0; d2 < 4; ++d2) {
      k_conv<<<dim3(NROW / 4), 256, 0, stream>>>(xbuf, cw, cb, xd + (size_t)d2 * SLOT_XD, d2);
      k_proj<<<dim3(512), 256, 0, stream>>>(xd + (size_t)d2 * SLOT_XD, xpw, dtw, dtbias,
                                            dtb + (size_t)d2 * SLOT_XD, bc + (size_t)d2 * SLOT_BC, d2);
    }
    k_scan1<<<dim3(NCH, 4, B_SZ), 64, 0, stream>>>(dtb, xd, bc, alog, hc, sdt, 0);
    k_scan2<<<dim3(1, 4, B_SZ), 64, 0, stream>>>(hc, sdt, alog, hstart, 0);
    for (int d2 = 0; d2 < 4; ++d2)
      k_scan3<<<dim3(NCH, 1, B_SZ), 64, 0, stream>>>(dtb + (size_t)d2 * SLOT_XD,
                                                     xd + (size_t)d2 * SLOT_XD,
                                                     bc + (size_t)d2 * SLOT_BC,
                                                     hstart + (size_t)d2 * SLOT_HC,
                                                     alog, dsk, ysum, d2);
  } else {
    for (int d2 = 0; d2 < 4; ++d2) {
      k_conv<<<dim3(NROW / 4), 256, 0, stream>>>(xbuf, cw, cb, xd, d2);
      k_proj<<<dim3(512), 256, 0, stream>>>(xd, xpw, dtw, dtbias, dtb, bc, d2);
      k_scan1<<<dim3(NCH, 1, B_SZ), 64, 0, stream>>>(dtb, xd, bc, alog, hc, sdt, d2);
      k_scan2<<<dim3(1, 1, B_SZ), 64, 0, stream>>>(hc, sdt, alog, hstart, d2);
      k_scan3<<<dim3(NCH, 1, B_SZ), 64, 0, stream>>>(dtb, xd, bc, hstart, alog, dsk, ysum, d2);
    }
  }
  k_final<<<dim3(512, 2), 64, 0, stream>>>(ysum, zbuf, ong, onb, opw, inp, out);
}

// Round 2
// 357.362 us; speedup vs baseline: 1.2791x; 1.2791x over previous
//
#include <hip/hip_runtime.h>
#include <hip/hip_bf16.h>
#include <cstdint>
#include <cstddef>

#define L_TOT 16384
#define B_SZ 2
#define NROW (B_SZ * L_TOT)
#define CHUNK 64
#define NCH (L_TOT / CHUNK)

static constexpr size_t SLOT_XD  = (size_t)NROW * 64;         // xd (u), later y, per-dir
static constexpr size_t SLOT_DBC = (size_t)NROW * 20;         // dtr(4)+B(8)+C(8) per-dir
static constexpr size_t SLOT_SDT = (size_t)B_SZ * NCH * 64;   // sum(dt) per chunk
static constexpr size_t SLOT_HC  = (size_t)B_SZ * NCH * 64 * 8; // chunk-local h -> h_start

// scan-position s -> original sequence index l (involution; verified in round 1).
__device__ __forceinline__ int tau_map(int dir, int s) {
  int j = (dir & 1) ? (L_TOT - 1 - s) : s;
  if (dir >= 2) j = ((j & 127) << 7) | (j >> 7);   // transpose of 128x128
  return j;
}
__device__ __forceinline__ float silu_f(float x) { return x / (1.f + __expf(-x)); }
__device__ __forceinline__ float softplus_f(float x) { return (x > 20.f) ? x : log1pf(__expf(x)); }

// ---------------- A: LayerNorm + in_proj (one 64-wide j-half per block) ----------------
__global__ void k_ln_inproj(const float* __restrict__ inp, const float* __restrict__ lng,
                            const float* __restrict__ lnb, const float* __restrict__ W,
                            float* __restrict__ xout, float* __restrict__ zout) {
  __shared__ float sm[64 * 65];
  const int t  = threadIdx.x;          // 0..63 = l within tile
  const int jh = blockIdx.y;           // 0 -> x half, 1 -> z half
  const int blk = blockIdx.x;          // 0..511
  const int b  = blk >> 8;
  const int l0 = (blk & 255) << 6;
  const float* ip = inp + (size_t)b * 64 * L_TOT + l0;
  for (int c = 0; c < 64; ++c)                       // coalesced along l
    sm[c * 65 + t] = ip[(size_t)c * L_TOT + t];
  __syncthreads();
  float xr[64];
  float m = 0.f;
#pragma unroll
  for (int c = 0; c < 64; ++c) { float v = sm[c * 65 + t]; xr[c] = v; m += v; }
  m *= 0.015625f;
  float var = 0.f;
#pragma unroll
  for (int c = 0; c < 64; ++c) { float dv = xr[c] - m; var += dv * dv; }
  var *= 0.015625f;
  const float rstd = rsqrtf(var + 1e-5f);
#pragma unroll
  for (int c = 0; c < 64; ++c) xr[c] = (xr[c] - m) * rstd * lng[c] + lnb[c];
  __syncthreads();
  const float* Wp = W + (size_t)(jh << 6) * 64;      // rows jh*64 .. jh*64+63
#pragma unroll 1
  for (int j = 0; j < 64; ++j) {
    float acc = 0.f;
#pragma unroll
    for (int c = 0; c < 64; ++c) acc += xr[c] * Wp[j * 64 + c];  // uniform s_loads
    sm[t * 65 + j] = acc;
  }
  __syncthreads();
  float* op = (jh ? zout : xout) + ((size_t)b * L_TOT + l0) * 64;
#pragma unroll 1
  for (int r = 0; r < 64; ++r)
    op[(size_t)r * 64 + t] = sm[r * 65 + t];         // coalesced store
}

// ------------- B: gather + causal conv(4) + SiLU fused with xproj (20 outs) -------------
__global__ void k_convproj(const float* __restrict__ xbuf, const float* __restrict__ cw,
                           const float* __restrict__ cb, const float* __restrict__ xpw,
                           float* __restrict__ xd_base, float* __restrict__ dbc_base,
                           int dir_base) {
  __shared__ float xt[64 * 65];
  __shared__ float dbl[64 * 20];
  const int t = threadIdx.x;           // 256
  const int slot = blockIdx.y;
  const int dir = dir_base + slot;
  const int blk = blockIdx.x;          // 512
  const int b = blk >> 8;
  const int s0 = (blk & 255) << 6;
  const int lane = t & 63;             // channel
  const int w = t >> 6;
  float wk[4];
#pragma unroll
  for (int k = 0; k < 4; ++k) wk[k] = cw[(dir * 64 + lane) * 4 + k];
  const float bconv = cb[dir * 64 + lane];
  float* xdp = xd_base + (size_t)slot * SLOT_XD + ((size_t)b * L_TOT + s0) * 64;
  const float* xb = xbuf + (size_t)b * L_TOT * 64;
#pragma unroll 1
  for (int rr = 0; rr < 16; ++rr) {
    const int r = rr * 4 + w;
    const int s = s0 + r;
    float acc = bconv;
#pragma unroll
    for (int k = 0; k < 4; ++k) {
      int j = s - 3 + k;
      if (j >= 0) {
        int l = tau_map(dir, j);
        acc += wk[k] * xb[(size_t)l * 64 + lane];
      }
    }
    acc = silu_f(acc);
    xt[r * 65 + lane] = acc;
    xdp[(size_t)r * 64 + lane] = acc;
  }
  __syncthreads();
  {  // xproj: wave g computes j = 5g..5g+4 for all 64 rows
    const int g = w;
    const int srow = lane;
    float acc5[5] = {0.f, 0.f, 0.f, 0.f, 0.f};
    const float* wp = xpw + ((size_t)dir * 20 + g * 5) * 64;
#pragma unroll 1
    for (int c = 0; c < 64; ++c) {
      float xv = xt[srow * 65 + c];
#pragma unroll
      for (int jj = 0; jj < 5; ++jj) acc5[jj] += xv * wp[jj * 64 + c];
    }
#pragma unroll
    for (int jj = 0; jj < 5; ++jj) dbl[srow * 20 + g * 5 + jj] = acc5[jj];
  }
  __syncthreads();
  float* dbp = dbc_base + (size_t)slot * SLOT_DBC + ((size_t)b * L_TOT + s0) * 20;
#pragma unroll 1
  for (int i = t; i < 1280; i += 256) dbp[i] = dbl[i];
}

// ---------------- S1: chunk-local scan (h=0 start), store h_end + sum(dt) ----------------
__global__ void k_scan1(const float* __restrict__ xd_base, const float* __restrict__ dbc_base,
                        const float* __restrict__ alog, const float* __restrict__ dtw,
                        const float* __restrict__ dtbias,
                        float* __restrict__ hcb, float* __restrict__ sdtb, int dir_base) {
  const int d = threadIdx.x;           // 64 channels
  const int ch = blockIdx.x;           // NCH chunks
  const int slot = blockIdx.y;
  const int dir = dir_base + slot;
  const int b = blockIdx.z;
  float a[8];
#pragma unroll
  for (int n = 0; n < 8; ++n) a[n] = -__expf(alog[((size_t)dir * 64 + d) * 8 + n]);
  float wdt[4];
#pragma unroll
  for (int r = 0; r < 4; ++r) wdt[r] = dtw[((size_t)dir * 64 + d) * 4 + r];
  const float bia = dtbias[dir * 64 + d];
  const float* up = xd_base + (size_t)slot * SLOT_XD + ((size_t)b * L_TOT + ch * CHUNK) * 64;
  const float* rp = dbc_base + (size_t)slot * SLOT_DBC + ((size_t)b * L_TOT + ch * CHUNK) * 20;
  float h[8] = {0,0,0,0,0,0,0,0};
  float sdt = 0.f;
#pragma unroll 4
  for (int s = 0; s < CHUNK; ++s) {
    float u = up[s * 64 + d];
    float dt = bia;
#pragma unroll
    for (int r = 0; r < 4; ++r) dt += rp[s * 20 + r] * wdt[r];
    dt = softplus_f(dt);
    sdt += dt;
    float du = dt * u;
#pragma unroll
    for (int n = 0; n < 8; ++n)
      h[n] = __expf(dt * a[n]) * h[n] + du * rp[s * 20 + 4 + n];
  }
  sdtb[(size_t)slot * SLOT_SDT + ((size_t)b * NCH + ch) * 64 + d] = sdt;
  float* hp = hcb + (size_t)slot * SLOT_HC + (((size_t)b * NCH + ch) * 64 + d) * 8;
#pragma unroll
  for (int n = 0; n < 8; ++n) hp[n] = h[n];
}

// ---- S2: parallel chunk stitch (Hillis-Steele over 256 chunks), exclusive in-place ----
__global__ void k_scan2(float* __restrict__ hcb, const float* __restrict__ sdtb,
                        const float* __restrict__ alog, int dir_base) {
  const int t = threadIdx.x;           // 256 = chunk index
  const int d = blockIdx.x >> 3;
  const int n = blockIdx.x & 7;
  const int slot = blockIdx.y;
  const int dir = dir_base + slot;
  const int b = blockIdx.z;
  const float a = -__expf(alog[((size_t)dir * 64 + d) * 8 + n]);
  float* hcp = hcb + (size_t)slot * SLOT_HC + (size_t)b * NCH * 512;
  const float* sdp = sdtb + (size_t)slot * SLOT_SDT + (size_t)b * NCH * 64;
  float e = __expf(a * sdp[(size_t)t * 64 + d]);
  float v = hcp[((size_t)t * 64 + d) * 8 + n];
  __shared__ float sE[256], sV[256];
  sE[t] = e; sV[t] = v;
  __syncthreads();
#pragma unroll
  for (int off = 1; off < 256; off <<= 1) {
    float pe = 1.f, pv = 0.f;
    if (t >= off) { pe = sE[t - off]; pv = sV[t - off]; }
    __syncthreads();
    v = fmaf(e, pv, v);     // compose: prev then self
    e = e * pe;
    sE[t] = e; sV[t] = v;
    __syncthreads();
  }
  const float hs = (t == 0) ? 0.f : sV[t - 1];   // exclusive = h_start for chunk t
  hcp[((size_t)t * 64 + d) * 8 + n] = hs;
}

// ---- S3: final scan with h_start; y = C.h + u*D; in-place over xd (or scatter-add) ----
__global__ void k_scan3(const float* xd_in, const float* __restrict__ dbc_base,
                        const float* __restrict__ hcb, const float* __restrict__ alog,
                        const float* __restrict__ dtw, const float* __restrict__ dtbias,
                        const float* __restrict__ dsk, float* y_base,
                        int dir_base, int scatter) {
  const int d = threadIdx.x;
  const int ch = blockIdx.x;
  const int slot = blockIdx.y;
  const int dir = dir_base + slot;
  const int b = blockIdx.z;
  float a[8];
#pragma unroll
  for (int n = 0; n < 8; ++n) a[n] = -__expf(alog[((size_t)dir * 64 + d) * 8 + n]);
  float wdt[4];
#pragma unroll
  for (int r = 0; r < 4; ++r) wdt[r] = dtw[((size_t)dir * 64 + d) * 4 + r];
  const float bia = dtbias[dir * 64 + d];
  const float Dv = dsk[dir * 64 + d];
  const float* up = xd_in + (size_t)slot * SLOT_XD + ((size_t)b * L_TOT + ch * CHUNK) * 64;
  const float* rp = dbc_base + (size_t)slot * SLOT_DBC + ((size_t)b * L_TOT + ch * CHUNK) * 20;
  const float* hsp = hcb + (size_t)slot * SLOT_HC + (((size_t)b * NCH + ch) * 64 + d) * 8;
  float h[8];
#pragma unroll
  for (int n = 0; n < 8; ++n) h[n] = hsp[n];
  const int sbase = ch * CHUNK;
#pragma unroll 4
  for (int s = 0; s < CHUNK; ++s) {
    float u = up[s * 64 + d];
    float dt = bia;
#pragma unroll
    for (int r = 0; r < 4; ++r) dt += rp[s * 20 + r] * wdt[r];
    dt = softplus_f(dt);
    float du = dt * u;
    float y = u * Dv;
#pragma unroll
    for (int n = 0; n < 8; ++n) {
      h[n] = __expf(dt * a[n]) * h[n] + du * rp[s * 20 + 4 + n];
      y = fmaf(rp[s * 20 + 12 + n], h[n], y);
    }
    if (scatter) {
      int l = tau_map(dir, sbase + s);
      float* yp = y_base + ((size_t)b * L_TOT + l) * 64 + d;
      *yp += y;                      // dirs serialized on the stream in this mode
    } else {
      y_base[(size_t)slot * SLOT_XD + ((size_t)b * L_TOT + sbase + s) * 64 + d] = y;
    }
  }
}

// ------- F: gather(sum over dirs) + /4 + LN + *silu(z) + out_proj + residual -------
__global__ void k_final(const float* __restrict__ ybase, const float* __restrict__ zbuf,
                        const float* __restrict__ ong, const float* __restrict__ onb,
                        const float* __restrict__ OW, const float* __restrict__ inp,
                        float* __restrict__ out, int gather) {
  __shared__ float ty[64 * 65];
  __shared__ float tz[64 * 65];
  const int t = threadIdx.x;           // 64
  const int jh = blockIdx.y;           // output-channel half (32 each)
  const int blk = blockIdx.x;
  const int b = blk >> 8;
  const int l0 = (blk & 255) << 6;
#pragma unroll 2
  for (int r = 0; r < 64; ++r) {
    const int l = l0 + r;
    float acc;
    if (gather) {
      acc = 0.f;
#pragma unroll
      for (int dir = 0; dir < 4; ++dir) {
        int s = tau_map(dir, l);
        acc += ybase[(size_t)dir * SLOT_XD + ((size_t)b * L_TOT + s) * 64 + t];
      }
    } else {
      acc = ybase[((size_t)b * L_TOT + l) * 64 + t];
    }
    ty[r * 65 + t] = acc;
    tz[r * 65 + t] = zbuf[((size_t)b * L_TOT + l) * 64 + t];
  }
  __syncthreads();
  float yr[64];
  float m = 0.f;
#pragma unroll
  for (int c = 0; c < 64; ++c) { float v = ty[t * 65 + c] * 0.25f; yr[c] = v; m += v; }
  m *= 0.015625f;
  float var = 0.f;
#pragma unroll
  for (int c = 0; c < 64; ++c) { float dv = yr[c] - m; var += dv * dv; }
  var *= 0.015625f;
  const float rstd = rsqrtf(var + 1e-5f);
#pragma unroll
  for (int c = 0; c < 64; ++c) {
    float yv = (yr[c] - m) * rstd * ong[c] + onb[c];
    yr[c] = yv * silu_f(tz[t * 65 + c]);
  }
  const int j0 = jh << 5;
#pragma unroll 1
  for (int j = j0; j < j0 + 32; ++j) {
    float acc = 0.f;
#pragma unroll
    for (int c = 0; c < 64; ++c) acc += yr[c] * OW[j * 64 + c];
    size_t o = ((size_t)b * 64 + j) * L_TOT + l0 + t;
    out[o] = acc + inp[o];     // coalesced along l
  }
}

extern "C" void kernel_launch(void* const* d_in, const int* in_sizes, int n_in,
                              void* d_out, int out_size, void* d_ws, size_t ws_size,
                              hipStream_t stream) {
  const float* inp    = (const float*)d_in[0];
  const float* lng    = (const float*)d_in[1];
  const float* lnb    = (const float*)d_in[2];
  const float* ipw    = (const float*)d_in[3];
  const float* cw     = (const float*)d_in[4];
  const float* cb     = (const float*)d_in[5];
  const float* xpw    = (const float*)d_in[6];
  const float* dtw    = (const float*)d_in[7];
  const float* dtbias = (const float*)d_in[8];
  const float* alog   = (const float*)d_in[9];
  const float* dsk    = (const float*)d_in[10];
  const float* ong    = (const float*)d_in[11];
  const float* onb    = (const float*)d_in[12];
  const float* opw    = (const float*)d_in[13];
  float* out = (float*)d_out;
  float* ws = (float*)d_ws;

  const size_t per_slot = SLOT_XD + SLOT_DBC + SLOT_SDT + SLOT_HC;
  const size_t need_batched = (2 * SLOT_XD + 4 * per_slot) * sizeof(float);     // ~65.5 MB

  if (ws_size >= need_batched) {
    size_t off = 0;
    float* xbuf = ws + off; off += SLOT_XD;
    float* zbuf = ws + off; off += SLOT_XD;
    float* xd   = ws + off; off += 4 * SLOT_XD;
    float* dbc  = ws + off; off += 4 * SLOT_DBC;
    float* sdt  = ws + off; off += 4 * SLOT_SDT;
    float* hc   = ws + off; off += 4 * SLOT_HC;

    k_ln_inproj<<<dim3(512, 2), 64, 0, stream>>>(inp, lng, lnb, ipw, xbuf, zbuf);
    k_convproj<<<dim3(512, 4), 256, 0, stream>>>(xbuf, cw, cb, xpw, xd, dbc, 0);
    k_scan1<<<dim3(NCH, 4, B_SZ), 64, 0, stream>>>(xd, dbc, alog, dtw, dtbias, hc, sdt, 0);
    k_scan2<<<dim3(512, 4, B_SZ), 256, 0, stream>>>(hc, sdt, alog, 0);
    k_scan3<<<dim3(NCH, 4, B_SZ), 64, 0, stream>>>(xd, dbc, hc, alog, dtw, dtbias, dsk,
                                                   xd, 0, 0);
    k_final<<<dim3(512, 2), 64, 0, stream>>>(xd, zbuf, ong, onb, opw, inp, out, 1);
  } else {
    size_t off = 0;
    float* xbuf = ws + off; off += SLOT_XD;
    float* zbuf = ws + off; off += SLOT_XD;
    float* ysum = ws + off; off += SLOT_XD;
    float* xd   = ws + off; off += SLOT_XD;
    float* dbc  = ws + off; off += SLOT_DBC;
    float* sdt  = ws + off; off += SLOT_SDT;
    float* hc   = ws + off; off += SLOT_HC;

    hipMemsetAsync(ysum, 0, SLOT_XD * sizeof(float), stream);
    k_ln_inproj<<<dim3(512, 2), 64, 0, stream>>>(inp, lng, lnb, ipw, xbuf, zbuf);
    for (int d2 = 0; d2 < 4; ++d2) {
      k_convproj<<<dim3(512, 1), 256, 0, stream>>>(xbuf, cw, cb, xpw, xd, dbc, d2);
      k_scan1<<<dim3(NCH, 1, B_SZ), 64, 0, stream>>>(xd, dbc, alog, dtw, dtbias, hc, sdt, d2);
      k_scan2<<<dim3(512, 1, B_SZ), 256, 0, stream>>>(hc, sdt, alog, d2);
      k_scan3<<<dim3(NCH, 1, B_SZ), 64, 0, stream>>>(xd, dbc, hc, alog, dtw, dtbias, dsk,
                                                     ysum, d2, 1);
    }
    k_final<<<dim3(512, 2), 64, 0, stream>>>(ysum, zbuf, ong, onb, opw, inp, out, 0);
  }
}

// Round 3
// 339.758 us; speedup vs baseline: 1.3454x; 1.0518x over previous
//
#include <hip/hip_runtime.h>
#include <hip/hip_bf16.h>
#include <cstdint>
#include <cstddef>

#define L_TOT 16384
#define B_SZ 2
#define NROW (B_SZ * L_TOT)
#define CHUNK 32
#define NCH (L_TOT / CHUNK)      // 512

static constexpr size_t SLOT_XD  = (size_t)NROW * 64;           // xd (u), later y, per-dir
static constexpr size_t SLOT_DBC = (size_t)NROW * 20;           // dtr(4)+B(8)+C(8) per-dir
static constexpr size_t SLOT_SDT = (size_t)B_SZ * 64 * NCH;     // sum(dt), layout [b][d][ch]
static constexpr size_t SLOT_HC  = (size_t)B_SZ * NCH * 64 * 8; // chunk h, layout [b][ch][d][n]

// scan-position s -> original sequence index l (involution; verified rounds 1-2).
__device__ __forceinline__ int tau_map(int dir, int s) {
  int j = (dir & 1) ? (L_TOT - 1 - s) : s;
  if (dir >= 2) j = ((j & 127) << 7) | (j >> 7);   // transpose of 128x128
  return j;
}
__device__ __forceinline__ float silu_f(float x) { return x / (1.f + __expf(-x)); }
__device__ __forceinline__ float softplus_f(float x) {
  return fmaxf(x, 0.f) + __logf(1.f + __expf(-fabsf(x)));
}

// ---------------- A: LayerNorm + in_proj (256 thr: 4 waves split the 128 j's) ----------------
__global__ void k_ln_inproj(const float* __restrict__ inp, const float* __restrict__ lng,
                            const float* __restrict__ lnb, const float* __restrict__ W,
                            float* __restrict__ xout, float* __restrict__ zout) {
  __shared__ float sm[64 * 65];   // input tile (transposed)
  __shared__ float so[64 * 65];   // output staging
  const int t = threadIdx.x;
  const int lane = t & 63;        // row l within tile (for LN) / store channel
  const int w = t >> 6;
  const int blk = blockIdx.x;     // 512
  const int b = blk >> 8;
  const int l0 = (blk & 255) << 6;
  const float* ip = inp + (size_t)b * 64 * L_TOT + l0;
#pragma unroll 1
  for (int cc = 0; cc < 16; ++cc) {
    int c = cc * 4 + w;
    sm[c * 65 + lane] = ip[(size_t)c * L_TOT + lane];   // coalesced along l
  }
  __syncthreads();
  float xr[64];
  float m = 0.f;
#pragma unroll
  for (int c = 0; c < 64; ++c) { float v = sm[c * 65 + lane]; xr[c] = v; m += v; }
  m *= 0.015625f;
  float var = 0.f;
#pragma unroll
  for (int c = 0; c < 64; ++c) { float dv = xr[c] - m; var += dv * dv; }
  var *= 0.015625f;
  const float rstd = rsqrtf(var + 1e-5f);
#pragma unroll
  for (int c = 0; c < 64; ++c) xr[c] = (xr[c] - m) * rstd * lng[c] + lnb[c];
  // x half: wave w computes j in [16w, 16w+16)
#pragma unroll 1
  for (int jj = 0; jj < 16; ++jj) {
    int j = w * 16 + jj;
    const float* wp = W + (size_t)j * 64;
    float acc = 0.f;
#pragma unroll
    for (int c = 0; c < 64; ++c) acc += xr[c] * wp[c];
    so[lane * 65 + j] = acc;
  }
  __syncthreads();
  {
    float* op = xout + ((size_t)b * L_TOT + l0) * 64;
#pragma unroll 1
    for (int rr = 0; rr < 16; ++rr) {
      int r = rr * 4 + w;
      op[(size_t)r * 64 + lane] = so[r * 65 + lane];
    }
  }
  __syncthreads();
  // z half
#pragma unroll 1
  for (int jj = 0; jj < 16; ++jj) {
    int j = w * 16 + jj;
    const float* wp = W + (size_t)(64 + j) * 64;
    float acc = 0.f;
#pragma unroll
    for (int c = 0; c < 64; ++c) acc += xr[c] * wp[c];
    so[lane * 65 + j] = acc;
  }
  __syncthreads();
  {
    float* op = zout + ((size_t)b * L_TOT + l0) * 64;
#pragma unroll 1
    for (int rr = 0; rr < 16; ++rr) {
      int r = rr * 4 + w;
      op[(size_t)r * 64 + lane] = so[r * 65 + lane];
    }
  }
}

// ------------- B: gather + causal conv(4) + SiLU fused with xproj (20 outs) -------------
__global__ void k_convproj(const float* __restrict__ xbuf, const float* __restrict__ cw,
                           const float* __restrict__ cb, const float* __restrict__ xpw,
                           float* __restrict__ xd_base, float* __restrict__ dbc_base,
                           int dir_base) {
  __shared__ float xt[64 * 65];
  __shared__ float dbl[64 * 20];
  const int t = threadIdx.x;           // 256
  const int slot = blockIdx.y;
  const int dir = dir_base + slot;
  const int blk = blockIdx.x;          // 512
  const int b = blk >> 8;
  const int s0 = (blk & 255) << 6;
  const int lane = t & 63;             // channel
  const int w = t >> 6;
  float wk[4];
#pragma unroll
  for (int k = 0; k < 4; ++k) wk[k] = cw[(dir * 64 + lane) * 4 + k];
  const float bconv = cb[dir * 64 + lane];
  float* xdp = xd_base + (size_t)slot * SLOT_XD + ((size_t)b * L_TOT + s0) * 64;
  const float* xb = xbuf + (size_t)b * L_TOT * 64;
#pragma unroll 1
  for (int rr = 0; rr < 16; ++rr) {
    const int r = rr * 4 + w;
    const int s = s0 + r;
    float acc = bconv;
#pragma unroll
    for (int k = 0; k < 4; ++k) {
      int j = s - 3 + k;
      if (j >= 0) {
        int l = tau_map(dir, j);
        acc += wk[k] * xb[(size_t)l * 64 + lane];
      }
    }
    acc = silu_f(acc);
    xt[r * 65 + lane] = acc;
    xdp[(size_t)r * 64 + lane] = acc;
  }
  __syncthreads();
  {  // xproj: wave g computes j = 5g..5g+4 for all 64 rows
    const int g = w;
    const int srow = lane;
    float acc5[5] = {0.f, 0.f, 0.f, 0.f, 0.f};
    const float* wp = xpw + ((size_t)dir * 20 + g * 5) * 64;
#pragma unroll 1
    for (int c = 0; c < 64; ++c) {
      float xv = xt[srow * 65 + c];
#pragma unroll
      for (int jj = 0; jj < 5; ++jj) acc5[jj] += xv * wp[jj * 64 + c];
    }
#pragma unroll
    for (int jj = 0; jj < 5; ++jj) dbl[srow * 20 + g * 5 + jj] = acc5[jj];
  }
  __syncthreads();
  float* dbp = dbc_base + (size_t)slot * SLOT_DBC + ((size_t)b * L_TOT + s0) * 20;
#pragma unroll 1
  for (int i = t; i < 1280; i += 256) dbp[i] = dbl[i];
}

// ------- S1: chunk-local scan, 4 chunk-waves/block, dbc staged in LDS -------
__global__ void k_scan1(const float* __restrict__ xd_base, const float* __restrict__ dbc_base,
                        const float* __restrict__ alog, const float* __restrict__ dtw,
                        const float* __restrict__ dtbias,
                        float* __restrict__ hcb, float* __restrict__ sdtb, int dir_base) {
  __shared__ float rpl[4 * CHUNK * 20];   // 10 KB
  const int t = threadIdx.x;              // 256
  const int w = t >> 6;
  const int d = t & 63;
  const int ch = blockIdx.x * 4 + w;
  const int slot = blockIdx.y;
  const int dir = dir_base + slot;
  const int b = blockIdx.z;
  const float* rblk = dbc_base + (size_t)slot * SLOT_DBC +
                      ((size_t)b * L_TOT + (size_t)blockIdx.x * 4 * CHUNK) * 20;
#pragma unroll 1
  for (int i = t; i < 4 * CHUNK * 20; i += 256) rpl[i] = rblk[i];
  __syncthreads();
  const float* rp = rpl + w * CHUNK * 20;
  float a[8];
#pragma unroll
  for (int n = 0; n < 8; ++n) a[n] = -__expf(alog[((size_t)dir * 64 + d) * 8 + n]);
  float wdt[4];
#pragma unroll
  for (int r = 0; r < 4; ++r) wdt[r] = dtw[((size_t)dir * 64 + d) * 4 + r];
  const float bia = dtbias[dir * 64 + d];
  const float* up = xd_base + (size_t)slot * SLOT_XD + ((size_t)b * L_TOT + ch * CHUNK) * 64;
  float h[8] = {0,0,0,0,0,0,0,0};
  float sdt = 0.f;
#pragma unroll 4
  for (int s = 0; s < CHUNK; ++s) {
    float u = up[s * 64 + d];
    float dt = bia;
#pragma unroll
    for (int r = 0; r < 4; ++r) dt = fmaf(rp[s * 20 + r], wdt[r], dt);
    dt = softplus_f(dt);
    sdt += dt;
    float du = dt * u;
#pragma unroll
    for (int n = 0; n < 8; ++n)
      h[n] = fmaf(__expf(dt * a[n]), h[n], du * rp[s * 20 + 4 + n]);
  }
  sdtb[(size_t)slot * SLOT_SDT + (((size_t)b * 64 + d) * NCH) + ch] = sdt;
  float* hp = hcb + (size_t)slot * SLOT_HC + (((size_t)b * NCH + ch) * 64 + d) * 8;
#pragma unroll
  for (int n = 0; n < 8; ++n) hp[n] = h[n];
}

// ---- S2: parallel chunk stitch (Hillis-Steele over 512 chunks), exclusive in-place ----
__global__ void k_scan2(float* __restrict__ hcb, const float* __restrict__ sdtb,
                        const float* __restrict__ alog, int dir_base) {
  const int t = threadIdx.x;           // 512 = chunk index
  const int d = blockIdx.x >> 3;
  const int n = blockIdx.x & 7;
  const int slot = blockIdx.y;
  const int dir = dir_base + slot;
  const int b = blockIdx.z;
  const float a = -__expf(alog[((size_t)dir * 64 + d) * 8 + n]);
  float* hcp = hcb + (size_t)slot * SLOT_HC + (size_t)b * NCH * 512;
  const float* sdp = sdtb + (size_t)slot * SLOT_SDT + ((size_t)b * 64 + d) * NCH;
  float e = __expf(a * sdp[t]);                       // coalesced
  float v = hcp[((size_t)t * 64 + d) * 8 + n];
  __shared__ float sE[NCH], sV[NCH];
  sE[t] = e; sV[t] = v;
  __syncthreads();
#pragma unroll
  for (int off = 1; off < NCH; off <<= 1) {
    float pe = 1.f, pv = 0.f;
    if (t >= off) { pe = sE[t - off]; pv = sV[t - off]; }
    __syncthreads();
    v = fmaf(e, pv, v);     // compose: prev then self
    e = e * pe;
    sE[t] = e; sV[t] = v;
    __syncthreads();
  }
  const float hs = (t == 0) ? 0.f : sV[t - 1];   // exclusive = h_start for chunk t
  hcp[((size_t)t * 64 + d) * 8 + n] = hs;
}

// ---- S3: final scan with h_start; y = C.h + u*D; in-place over xd (or scatter-add) ----
__global__ void k_scan3(const float* xd_in, const float* __restrict__ dbc_base,
                        const float* __restrict__ hcb, const float* __restrict__ alog,
                        const float* __restrict__ dtw, const float* __restrict__ dtbias,
                        const float* __restrict__ dsk, float* y_base,
                        int dir_base, int scatter) {
  __shared__ float rpl[4 * CHUNK * 20];
  const int t = threadIdx.x;              // 256
  const int w = t >> 6;
  const int d = t & 63;
  const int ch = blockIdx.x * 4 + w;
  const int slot = blockIdx.y;
  const int dir = dir_base + slot;
  const int b = blockIdx.z;
  const float* rblk = dbc_base + (size_t)slot * SLOT_DBC +
                      ((size_t)b * L_TOT + (size_t)blockIdx.x * 4 * CHUNK) * 20;
#pragma unroll 1
  for (int i = t; i < 4 * CHUNK * 20; i += 256) rpl[i] = rblk[i];
  __syncthreads();
  const float* rp = rpl + w * CHUNK * 20;
  float a[8];
#pragma unroll
  for (int n = 0; n < 8; ++n) a[n] = -__expf(alog[((size_t)dir * 64 + d) * 8 + n]);
  float wdt[4];
#pragma unroll
  for (int r = 0; r < 4; ++r) wdt[r] = dtw[((size_t)dir * 64 + d) * 4 + r];
  const float bia = dtbias[dir * 64 + d];
  const float Dv = dsk[dir * 64 + d];
  const float* up = xd_in + (size_t)slot * SLOT_XD + ((size_t)b * L_TOT + ch * CHUNK) * 64;
  const float* hsp = hcb + (size_t)slot * SLOT_HC + (((size_t)b * NCH + ch) * 64 + d) * 8;
  float h[8];
#pragma unroll
  for (int n = 0; n < 8; ++n) h[n] = hsp[n];
  const int sbase = ch * CHUNK;
#pragma unroll 4
  for (int s = 0; s < CHUNK; ++s) {
    float u = up[s * 64 + d];
    float dt = bia;
#pragma unroll
    for (int r = 0; r < 4; ++r) dt = fmaf(rp[s * 20 + r], wdt[r], dt);
    dt = softplus_f(dt);
    float du = dt * u;
    float y = u * Dv;
#pragma unroll
    for (int n = 0; n < 8; ++n) {
      h[n] = fmaf(__expf(dt * a[n]), h[n], du * rp[s * 20 + 4 + n]);
      y = fmaf(rp[s * 20 + 12 + n], h[n], y);
    }
    if (scatter) {
      int l = tau_map(dir, sbase + s);
      float* yp = y_base + ((size_t)b * L_TOT + l) * 64 + d;
      *yp += y;                      // dirs serialized on the stream in this mode
    } else {
      y_base[(size_t)slot * SLOT_XD + ((size_t)b * L_TOT + sbase + s) * 64 + d] = y;
    }
  }
}

// ------- F: gather(sum over dirs) + /4 + LN + *silu(z) + out_proj + residual -------
__global__ void k_final(const float* __restrict__ ybase, const float* __restrict__ zbuf,
                        const float* __restrict__ ong, const float* __restrict__ onb,
                        const float* __restrict__ OW, const float* __restrict__ inp,
                        float* __restrict__ out, int gather) {
  __shared__ float ty[64 * 65];
  __shared__ float tz[64 * 65];
  const int t = threadIdx.x;           // 256
  const int lane = t & 63;
  const int w = t >> 6;
  const int blk = blockIdx.x;
  const int b = blk >> 8;
  const int l0 = (blk & 255) << 6;
#pragma unroll 1
  for (int rr = 0; rr < 16; ++rr) {
    const int r = rr * 4 + w;
    const int l = l0 + r;
    float acc;
    if (gather) {
      acc = 0.f;
#pragma unroll
      for (int dir = 0; dir < 4; ++dir) {
        int s = tau_map(dir, l);
        acc += ybase[(size_t)dir * SLOT_XD + ((size_t)b * L_TOT + s) * 64 + lane];
      }
    } else {
      acc = ybase[((size_t)b * L_TOT + l) * 64 + lane];
    }
    ty[r * 65 + lane] = acc;
    tz[r * 65 + lane] = zbuf[((size_t)b * L_TOT + l) * 64 + lane];
  }
  __syncthreads();
  float yr[64];   // row = lane
  float m = 0.f;
#pragma unroll
  for (int c = 0; c < 64; ++c) { float v = ty[lane * 65 + c] * 0.25f; yr[c] = v; m += v; }
  m *= 0.015625f;
  float var = 0.f;
#pragma unroll
  for (int c = 0; c < 64; ++c) { float dv = yr[c] - m; var += dv * dv; }
  var *= 0.015625f;
  const float rstd = rsqrtf(var + 1e-5f);
#pragma unroll
  for (int c = 0; c < 64; ++c) {
    float yv = (yr[c] - m) * rstd * ong[c] + onb[c];
    yr[c] = yv * silu_f(tz[lane * 65 + c]);
  }
  __syncthreads();   // ty/tz now free for restaging
  // out_proj: wave w computes j in [16w, 16w+16) for its row, stage to ty[row][j]
#pragma unroll 1
  for (int jj = 0; jj < 16; ++jj) {
    int j = w * 16 + jj;
    const float* wp = OW + (size_t)j * 64;
    float acc = 0.f;
#pragma unroll
    for (int c = 0; c < 64; ++c) acc += yr[c] * wp[c];
    ty[lane * 65 + j] = acc;
  }
  __syncthreads();
#pragma unroll 1
  for (int jj = 0; jj < 16; ++jj) {
    int j = jj * 4 + w;
    size_t o = ((size_t)b * 64 + j) * L_TOT + l0 + lane;
    out[o] = ty[lane * 65 + j] + inp[o];   // coalesced along l
  }
}

extern "C" void kernel_launch(void* const* d_in, const int* in_sizes, int n_in,
                              void* d_out, int out_size, void* d_ws, size_t ws_size,
                              hipStream_t stream) {
  const float* inp    = (const float*)d_in[0];
  const float* lng    = (const float*)d_in[1];
  const float* lnb    = (const float*)d_in[2];
  const float* ipw    = (const float*)d_in[3];
  const float* cw     = (const float*)d_in[4];
  const float* cb     = (const float*)d_in[5];
  const float* xpw    = (const float*)d_in[6];
  const float* dtw    = (const float*)d_in[7];
  const float* dtbias = (const float*)d_in[8];
  const float* alog   = (const float*)d_in[9];
  const float* dsk    = (const float*)d_in[10];
  const float* ong    = (const float*)d_in[11];
  const float* onb    = (const float*)d_in[12];
  const float* opw    = (const float*)d_in[13];
  float* out = (float*)d_out;
  float* ws = (float*)d_ws;

  // batched layout: hc aliases xbuf (dead after convproj); 4*SLOT_HC == SLOT_XD
  const size_t need_batched = (6 * SLOT_XD + 4 * SLOT_DBC + 4 * SLOT_SDT) * sizeof(float);

  if (ws_size >= need_batched) {
    size_t off = 0;
    float* xbuf = ws + off; off += SLOT_XD;          // also hc after convproj
    float* zbuf = ws + off; off += SLOT_XD;
    float* xd   = ws + off; off += 4 * SLOT_XD;
    float* dbc  = ws + off; off += 4 * SLOT_DBC;
    float* sdt  = ws + off; off += 4 * SLOT_SDT;
    float* hc   = xbuf;

    k_ln_inproj<<<dim3(512), 256, 0, stream>>>(inp, lng, lnb, ipw, xbuf, zbuf);
    k_convproj<<<dim3(512, 4), 256, 0, stream>>>(xbuf, cw, cb, xpw, xd, dbc, 0);
    k_scan1<<<dim3(NCH / 4, 4, B_SZ), 256, 0, stream>>>(xd, dbc, alog, dtw, dtbias, hc, sdt, 0);
    k_scan2<<<dim3(512, 4, B_SZ), NCH, 0, stream>>>(hc, sdt, alog, 0);
    k_scan3<<<dim3(NCH / 4, 4, B_SZ), 256, 0, stream>>>(xd, dbc, hc, alog, dtw, dtbias, dsk,
                                                        xd, 0, 0);
    k_final<<<dim3(512), 256, 0, stream>>>(xd, zbuf, ong, onb, opw, inp, out, 1);
  } else {
    size_t off = 0;
    float* xbuf = ws + off; off += SLOT_XD;
    float* zbuf = ws + off; off += SLOT_XD;
    float* ysum = ws + off; off += SLOT_XD;
    float* xd   = ws + off; off += SLOT_XD;
    float* dbc  = ws + off; off += SLOT_DBC;
    float* sdt  = ws + off; off += SLOT_SDT;
    float* hc   = ws + off; off += SLOT_HC;

    hipMemsetAsync(ysum, 0, SLOT_XD * sizeof(float), stream);
    k_ln_inproj<<<dim3(512), 256, 0, stream>>>(inp, lng, lnb, ipw, xbuf, zbuf);
    for (int d2 = 0; d2 < 4; ++d2) {
      k_convproj<<<dim3(512, 1), 256, 0, stream>>>(xbuf, cw, cb, xpw, xd, dbc, d2);
      k_scan1<<<dim3(NCH / 4, 1, B_SZ), 256, 0, stream>>>(xd, dbc, alog, dtw, dtbias, hc, sdt, d2);
      k_scan2<<<dim3(512, 1, B_SZ), NCH, 0, stream>>>(hc, sdt, alog, d2);
      k_scan3<<<dim3(NCH / 4, 1, B_SZ), 256, 0, stream>>>(xd, dbc, hc, alog, dtw, dtbias, dsk,
                                                          ysum, d2, 1);
    }
    k_final<<<dim3(512), 256, 0, stream>>>(ysum, zbuf, ong, onb, opw, inp, out, 0);
  }
}

// Round 4
// 338.875 us; speedup vs baseline: 1.3489x; 1.0026x over previous
//
#include <hip/hip_runtime.h>
#include <hip/hip_bf16.h>
#include <cstdint>
#include <cstddef>

#define L_TOT 16384
#define B_SZ 2
#define NROW (B_SZ * L_TOT)
#define CHUNK 32
#define NCH (L_TOT / CHUNK)      // 512

static constexpr size_t SLOT_XD  = (size_t)NROW * 64;           // xd (u), later y, per-dir
static constexpr size_t SLOT_DBC = (size_t)NROW * 20;           // dtr(4)+B(8)+C(8) per-dir
static constexpr size_t SLOT_SDT = (size_t)B_SZ * 64 * NCH;     // sum(dt), layout [b][d][ch]
static constexpr size_t SLOT_HC  = (size_t)B_SZ * NCH * 64 * 8; // chunk h, layout [b][ch][d][n]

// scan-position s -> original sequence index l (involution; verified rounds 1-2).
__device__ __forceinline__ int tau_map(int dir, int s) {
  int j = (dir & 1) ? (L_TOT - 1 - s) : s;
  if (dir >= 2) j = ((j & 127) << 7) | (j >> 7);   // transpose of 128x128
  return j;
}
__device__ __forceinline__ float silu_f(float x) { return x / (1.f + __expf(-x)); }
__device__ __forceinline__ float softplus_f(float x) {
  return fmaxf(x, 0.f) + __logf(1.f + __expf(-fabsf(x)));
}

// ---------------- A: LayerNorm + in_proj (256 thr: 4 waves split the 128 j's) ----------------
// __launch_bounds__(256,4): 128-VGPR cap -> xr[64] stays in registers (round-3 spill fix).
__global__ void __launch_bounds__(256, 4)
k_ln_inproj(const float* __restrict__ inp, const float* __restrict__ lng,
            const float* __restrict__ lnb, const float* __restrict__ W,
            float* __restrict__ xout, float* __restrict__ zout) {
  __shared__ float sm[64 * 65];   // input tile (transposed)
  __shared__ float so[64 * 65];   // output staging
  const int t = threadIdx.x;
  const int lane = t & 63;        // row l within tile (for LN) / store channel
  const int w = t >> 6;
  const int blk = blockIdx.x;     // 512
  const int b = blk >> 8;
  const int l0 = (blk & 255) << 6;
  const float* ip = inp + (size_t)b * 64 * L_TOT + l0;
#pragma unroll 1
  for (int cc = 0; cc < 16; ++cc) {
    int c = cc * 4 + w;
    sm[c * 65 + lane] = ip[(size_t)c * L_TOT + lane];   // coalesced along l
  }
  __syncthreads();
  float xr[64];
  float m = 0.f;
#pragma unroll
  for (int c = 0; c < 64; ++c) { float v = sm[c * 65 + lane]; xr[c] = v; m += v; }
  m *= 0.015625f;
  float var = 0.f;
#pragma unroll
  for (int c = 0; c < 64; ++c) { float dv = xr[c] - m; var += dv * dv; }
  var *= 0.015625f;
  const float rstd = rsqrtf(var + 1e-5f);
#pragma unroll
  for (int c = 0; c < 64; ++c) xr[c] = (xr[c] - m) * rstd * lng[c] + lnb[c];
  // x half: wave w computes j in [16w, 16w+16)
#pragma unroll 1
  for (int jj = 0; jj < 16; ++jj) {
    int j = w * 16 + jj;
    const float* wp = W + (size_t)j * 64;
    float acc = 0.f;
#pragma unroll
    for (int c = 0; c < 64; ++c) acc += xr[c] * wp[c];
    so[lane * 65 + j] = acc;
  }
  __syncthreads();
  {
    float* op = xout + ((size_t)b * L_TOT + l0) * 64;
#pragma unroll 1
    for (int rr = 0; rr < 16; ++rr) {
      int r = rr * 4 + w;
      op[(size_t)r * 64 + lane] = so[r * 65 + lane];
    }
  }
  __syncthreads();
  // z half
#pragma unroll 1
  for (int jj = 0; jj < 16; ++jj) {
    int j = w * 16 + jj;
    const float* wp = W + (size_t)(64 + j) * 64;
    float acc = 0.f;
#pragma unroll
    for (int c = 0; c < 64; ++c) acc += xr[c] * wp[c];
    so[lane * 65 + j] = acc;
  }
  __syncthreads();
  {
    float* op = zout + ((size_t)b * L_TOT + l0) * 64;
#pragma unroll 1
    for (int rr = 0; rr < 16; ++rr) {
      int r = rr * 4 + w;
      op[(size_t)r * 64 + lane] = so[r * 65 + lane];
    }
  }
}

// ------------- B: gather + causal conv(4) + SiLU fused with xproj (20 outs) -------------
__global__ void __launch_bounds__(256, 4)
k_convproj(const float* __restrict__ xbuf, const float* __restrict__ cw,
           const float* __restrict__ cb, const float* __restrict__ xpw,
           float* __restrict__ xd_base, float* __restrict__ dbc_base,
           int dir_base) {
  __shared__ float xt[64 * 65];
  __shared__ float dbl[64 * 20];
  const int t = threadIdx.x;           // 256
  const int slot = blockIdx.y;
  const int dir = dir_base + slot;
  const int blk = blockIdx.x;          // 512
  const int b = blk >> 8;
  const int s0 = (blk & 255) << 6;
  const int lane = t & 63;             // channel
  const int w = t >> 6;
  float wk[4];
#pragma unroll
  for (int k = 0; k < 4; ++k) wk[k] = cw[(dir * 64 + lane) * 4 + k];
  const float bconv = cb[dir * 64 + lane];
  float* xdp = xd_base + (size_t)slot * SLOT_XD + ((size_t)b * L_TOT + s0) * 64;
  const float* xb = xbuf + (size_t)b * L_TOT * 64;
#pragma unroll 1
  for (int rr = 0; rr < 16; ++rr) {
    const int r = rr * 4 + w;
    const int s = s0 + r;
    float acc = bconv;
#pragma unroll
    for (int k = 0; k < 4; ++k) {
      int j = s - 3 + k;
      if (j >= 0) {
        int l = tau_map(dir, j);
        acc += wk[k] * xb[(size_t)l * 64 + lane];
      }
    }
    acc = silu_f(acc);
    xt[r * 65 + lane] = acc;
    xdp[(size_t)r * 64 + lane] = acc;
  }
  __syncthreads();
  {  // xproj: wave g computes j = 5g..5g+4 for all 64 rows
    const int g = w;
    const int srow = lane;
    float acc5[5] = {0.f, 0.f, 0.f, 0.f, 0.f};
    const float* wp = xpw + ((size_t)dir * 20 + g * 5) * 64;
#pragma unroll 1
    for (int c = 0; c < 64; ++c) {
      float xv = xt[srow * 65 + c];
#pragma unroll
      for (int jj = 0; jj < 5; ++jj) acc5[jj] += xv * wp[jj * 64 + c];
    }
#pragma unroll
    for (int jj = 0; jj < 5; ++jj) dbl[srow * 20 + g * 5 + jj] = acc5[jj];
  }
  __syncthreads();
  float* dbp = dbc_base + (size_t)slot * SLOT_DBC + ((size_t)b * L_TOT + s0) * 20;
#pragma unroll 1
  for (int i = t; i < 1280; i += 256) dbp[i] = dbl[i];
}

// ------- S1: chunk-local scan, 4 chunk-waves/block, dbc staged in LDS -------
__global__ void __launch_bounds__(256, 4)
k_scan1(const float* __restrict__ xd_base, const float* __restrict__ dbc_base,
        const float* __restrict__ alog, const float* __restrict__ dtw,
        const float* __restrict__ dtbias,
        float* __restrict__ hcb, float* __restrict__ sdtb, int dir_base) {
  __shared__ float rpl[4 * CHUNK * 20];   // 10 KB
  const int t = threadIdx.x;              // 256
  const int w = t >> 6;
  const int d = t & 63;
  const int ch = blockIdx.x * 4 + w;
  const int slot = blockIdx.y;
  const int dir = dir_base + slot;
  const int b = blockIdx.z;
  const float* rblk = dbc_base + (size_t)slot * SLOT_DBC +
                      ((size_t)b * L_TOT + (size_t)blockIdx.x * 4 * CHUNK) * 20;
#pragma unroll 1
  for (int i = t; i < 4 * CHUNK * 20; i += 256) rpl[i] = rblk[i];
  __syncthreads();
  const float* rp = rpl + w * CHUNK * 20;
  float a[8];
#pragma unroll
  for (int n = 0; n < 8; ++n) a[n] = -__expf(alog[((size_t)dir * 64 + d) * 8 + n]);
  float wdt[4];
#pragma unroll
  for (int r = 0; r < 4; ++r) wdt[r] = dtw[((size_t)dir * 64 + d) * 4 + r];
  const float bia = dtbias[dir * 64 + d];
  const float* up = xd_base + (size_t)slot * SLOT_XD + ((size_t)b * L_TOT + ch * CHUNK) * 64;
  float h[8] = {0,0,0,0,0,0,0,0};
  float sdt = 0.f;
#pragma unroll 4
  for (int s = 0; s < CHUNK; ++s) {
    float u = up[s * 64 + d];
    float dt = bia;
#pragma unroll
    for (int r = 0; r < 4; ++r) dt = fmaf(rp[s * 20 + r], wdt[r], dt);
    dt = softplus_f(dt);
    sdt += dt;
    float du = dt * u;
#pragma unroll
    for (int n = 0; n < 8; ++n)
      h[n] = fmaf(__expf(dt * a[n]), h[n], du * rp[s * 20 + 4 + n]);
  }
  sdtb[(size_t)slot * SLOT_SDT + (((size_t)b * 64 + d) * NCH) + ch] = sdt;
  float* hp = hcb + (size_t)slot * SLOT_HC + (((size_t)b * NCH + ch) * 64 + d) * 8;
#pragma unroll
  for (int n = 0; n < 8; ++n) hp[n] = h[n];
}

// ---- S2: parallel chunk stitch (Hillis-Steele over 512 chunks), exclusive in-place ----
__global__ void k_scan2(float* __restrict__ hcb, const float* __restrict__ sdtb,
                        const float* __restrict__ alog, int dir_base) {
  const int t = threadIdx.x;           // 512 = chunk index
  const int d = blockIdx.x >> 3;
  const int n = blockIdx.x & 7;
  const int slot = blockIdx.y;
  const int dir = dir_base + slot;
  const int b = blockIdx.z;
  const float a = -__expf(alog[((size_t)dir * 64 + d) * 8 + n]);
  float* hcp = hcb + (size_t)slot * SLOT_HC + (size_t)b * NCH * 512;
  const float* sdp = sdtb + (size_t)slot * SLOT_SDT + ((size_t)b * 64 + d) * NCH;
  float e = __expf(a * sdp[t]);                       // coalesced
  float v = hcp[((size_t)t * 64 + d) * 8 + n];
  __shared__ float sE[NCH], sV[NCH];
  sE[t] = e; sV[t] = v;
  __syncthreads();
#pragma unroll
  for (int off = 1; off < NCH; off <<= 1) {
    float pe = 1.f, pv = 0.f;
    if (t >= off) { pe = sE[t - off]; pv = sV[t - off]; }
    __syncthreads();
    v = fmaf(e, pv, v);     // compose: prev then self
    e = e * pe;
    sE[t] = e; sV[t] = v;
    __syncthreads();
  }
  const float hs = (t == 0) ? 0.f : sV[t - 1];   // exclusive = h_start for chunk t
  hcp[((size_t)t * 64 + d) * 8 + n] = hs;
}

// ---- S3: final scan with h_start; y = C.h + u*D; in-place over xd (or scatter-add) ----
__global__ void __launch_bounds__(256, 4)
k_scan3(const float* xd_in, const float* __restrict__ dbc_base,
        const float* __restrict__ hcb, const float* __restrict__ alog,
        const float* __restrict__ dtw, const float* __restrict__ dtbias,
        const float* __restrict__ dsk, float* y_base,
        int dir_base, int scatter) {
  __shared__ float rpl[4 * CHUNK * 20];
  const int t = threadIdx.x;              // 256
  const int w = t >> 6;
  const int d = t & 63;
  const int ch = blockIdx.x * 4 + w;
  const int slot = blockIdx.y;
  const int dir = dir_base + slot;
  const int b = blockIdx.z;
  const float* rblk = dbc_base + (size_t)slot * SLOT_DBC +
                      ((size_t)b * L_TOT + (size_t)blockIdx.x * 4 * CHUNK) * 20;
#pragma unroll 1
  for (int i = t; i < 4 * CHUNK * 20; i += 256) rpl[i] = rblk[i];
  __syncthreads();
  const float* rp = rpl + w * CHUNK * 20;
  float a[8];
#pragma unroll
  for (int n = 0; n < 8; ++n) a[n] = -__expf(alog[((size_t)dir * 64 + d) * 8 + n]);
  float wdt[4];
#pragma unroll
  for (int r = 0; r < 4; ++r) wdt[r] = dtw[((size_t)dir * 64 + d) * 4 + r];
  const float bia = dtbias[dir * 64 + d];
  const float Dv = dsk[dir * 64 + d];
  const float* up = xd_in + (size_t)slot * SLOT_XD + ((size_t)b * L_TOT + ch * CHUNK) * 64;
  const float* hsp = hcb + (size_t)slot * SLOT_HC + (((size_t)b * NCH + ch) * 64 + d) * 8;
  float h[8];
#pragma unroll
  for (int n = 0; n < 8; ++n) h[n] = hsp[n];
  const int sbase = ch * CHUNK;
#pragma unroll 4
  for (int s = 0; s < CHUNK; ++s) {
    float u = up[s * 64 + d];
    float dt = bia;
#pragma unroll
    for (int r = 0; r < 4; ++r) dt = fmaf(rp[s * 20 + r], wdt[r], dt);
    dt = softplus_f(dt);
    float du = dt * u;
    float y = u * Dv;
#pragma unroll
    for (int n = 0; n < 8; ++n) {
      h[n] = fmaf(__expf(dt * a[n]), h[n], du * rp[s * 20 + 4 + n]);
      y = fmaf(rp[s * 20 + 12 + n], h[n], y);
    }
    if (scatter) {
      int l = tau_map(dir, sbase + s);
      float* yp = y_base + ((size_t)b * L_TOT + l) * 64 + d;
      *yp += y;                      // dirs serialized on the stream in this mode
    } else {
      y_base[(size_t)slot * SLOT_XD + ((size_t)b * L_TOT + sbase + s) * 64 + d] = y;
    }
  }
}

// ------- F: gather(sum over dirs) + /4 + LN + *silu(z) + out_proj + residual -------
// __launch_bounds__(256,4): 128-VGPR cap -> yr[64] stays in registers (round-3 spill fix).
__global__ void __launch_bounds__(256, 4)
k_final(const float* __restrict__ ybase, const float* __restrict__ zbuf,
        const float* __restrict__ ong, const float* __restrict__ onb,
        const float* __restrict__ OW, const float* __restrict__ inp,
        float* __restrict__ out, int gather) {
  __shared__ float ty[64 * 65];
  __shared__ float tz[64 * 65];
  const int t = threadIdx.x;           // 256
  const int lane = t & 63;
  const int w = t >> 6;
  const int blk = blockIdx.x;
  const int b = blk >> 8;
  const int l0 = (blk & 255) << 6;
#pragma unroll 1
  for (int rr = 0; rr < 16; ++rr) {
    const int r = rr * 4 + w;
    const int l = l0 + r;
    float acc;
    if (gather) {
      acc = 0.f;
#pragma unroll
      for (int dir = 0; dir < 4; ++dir) {
        int s = tau_map(dir, l);
        acc += ybase[(size_t)dir * SLOT_XD + ((size_t)b * L_TOT + s) * 64 + lane];
      }
    } else {
      acc = ybase[((size_t)b * L_TOT + l) * 64 + lane];
    }
    ty[r * 65 + lane] = acc;
    tz[r * 65 + lane] = zbuf[((size_t)b * L_TOT + l) * 64 + lane];
  }
  __syncthreads();
  float yr[64];   // row = lane
  float m = 0.f;
#pragma unroll
  for (int c = 0; c < 64; ++c) { float v = ty[lane * 65 + c] * 0.25f; yr[c] = v; m += v; }
  m *= 0.015625f;
  float var = 0.f;
#pragma unroll
  for (int c = 0; c < 64; ++c) { float dv = yr[c] - m; var += dv * dv; }
  var *= 0.015625f;
  const float rstd = rsqrtf(var + 1e-5f);
#pragma unroll
  for (int c = 0; c < 64; ++c) {
    float yv = (yr[c] - m) * rstd * ong[c] + onb[c];
    yr[c] = yv * silu_f(tz[lane * 65 + c]);
  }
  __syncthreads();   // ty/tz now free for restaging
  // out_proj: wave w computes j in [16w, 16w+16) for its row, stage to ty[row][j]
#pragma unroll 1
  for (int jj = 0; jj < 16; ++jj) {
    int j = w * 16 + jj;
    const float* wp = OW + (size_t)j * 64;
    float acc = 0.f;
#pragma unroll
    for (int c = 0; c < 64; ++c) acc += yr[c] * wp[c];
    ty[lane * 65 + j] = acc;
  }
  __syncthreads();
#pragma unroll 1
  for (int jj = 0; jj < 16; ++jj) {
    int j = jj * 4 + w;
    size_t o = ((size_t)b * 64 + j) * L_TOT + l0 + lane;
    out[o] = ty[lane * 65 + j] + inp[o];   // coalesced along l
  }
}

extern "C" void kernel_launch(void* const* d_in, const int* in_sizes, int n_in,
                              void* d_out, int out_size, void* d_ws, size_t ws_size,
                              hipStream_t stream) {
  const float* inp    = (const float*)d_in[0];
  const float* lng    = (const float*)d_in[1];
  const float* lnb    = (const float*)d_in[2];
  const float* ipw    = (const float*)d_in[3];
  const float* cw     = (const float*)d_in[4];
  const float* cb     = (const float*)d_in[5];
  const float* xpw    = (const float*)d_in[6];
  const float* dtw    = (const float*)d_in[7];
  const float* dtbias = (const float*)d_in[8];
  const float* alog   = (const float*)d_in[9];
  const float* dsk    = (const float*)d_in[10];
  const float* ong    = (const float*)d_in[11];
  const float* onb    = (const float*)d_in[12];
  const float* opw    = (const float*)d_in[13];
  float* out = (float*)d_out;
  float* ws = (float*)d_ws;

  // batched layout: hc aliases xbuf (dead after convproj); 4*SLOT_HC == SLOT_XD
  const size_t need_batched = (6 * SLOT_XD + 4 * SLOT_DBC + 4 * SLOT_SDT) * sizeof(float);

  if (ws_size >= need_batched) {
    size_t off = 0;
    float* xbuf = ws + off; off += SLOT_XD;          // also hc after convproj
    float* zbuf = ws + off; off += SLOT_XD;
    float* xd   = ws + off; off += 4 * SLOT_XD;
    float* dbc  = ws + off; off += 4 * SLOT_DBC;
    float* sdt  = ws + off; off += 4 * SLOT_SDT;
    float* hc   = xbuf;

    k_ln_inproj<<<dim3(512), 256, 0, stream>>>(inp, lng, lnb, ipw, xbuf, zbuf);
    k_convproj<<<dim3(512, 4), 256, 0, stream>>>(xbuf, cw, cb, xpw, xd, dbc, 0);
    k_scan1<<<dim3(NCH / 4, 4, B_SZ), 256, 0, stream>>>(xd, dbc, alog, dtw, dtbias, hc, sdt, 0);
    k_scan2<<<dim3(512, 4, B_SZ), NCH, 0, stream>>>(hc, sdt, alog, 0);
    k_scan3<<<dim3(NCH / 4, 4, B_SZ), 256, 0, stream>>>(xd, dbc, hc, alog, dtw, dtbias, dsk,
                                                        xd, 0, 0);
    k_final<<<dim3(512), 256, 0, stream>>>(xd, zbuf, ong, onb, opw, inp, out, 1);
  } else {
    size_t off = 0;
    float* xbuf = ws + off; off += SLOT_XD;
    float* zbuf = ws + off; off += SLOT_XD;
    float* ysum = ws + off; off += SLOT_XD;
    float* xd   = ws + off; off += SLOT_XD;
    float* dbc  = ws + off; off += SLOT_DBC;
    float* sdt  = ws + off; off += SLOT_SDT;
    float* hc   = ws + off; off += SLOT_HC;

    hipMemsetAsync(ysum, 0, SLOT_XD * sizeof(float), stream);
    k_ln_inproj<<<dim3(512), 256, 0, stream>>>(inp, lng, lnb, ipw, xbuf, zbuf);
    for (int d2 = 0; d2 < 4; ++d2) {
      k_convproj<<<dim3(512, 1), 256, 0, stream>>>(xbuf, cw, cb, xpw, xd, dbc, d2);
      k_scan1<<<dim3(NCH / 4, 1, B_SZ), 256, 0, stream>>>(xd, dbc, alog, dtw, dtbias, hc, sdt, d2);
      k_scan2<<<dim3(512, 1, B_SZ), NCH, 0, stream>>>(hc, sdt, alog, d2);
      k_scan3<<<dim3(NCH / 4, 1, B_SZ), 256, 0, stream>>>(xd, dbc, hc, alog, dtw, dtbias, dsk,
                                                          ysum, d2, 1);
    }
    k_final<<<dim3(512), 256, 0, stream>>>(ysum, zbuf, ong, onb, opw, inp, out, 0);
  }
}

// Round 5
// 290.618 us; speedup vs baseline: 1.5728x; 1.1661x over previous
//
#include <hip/hip_runtime.h>
#include <hip/hip_bf16.h>
#include <cstdint>
#include <cstddef>

#define L_TOT 16384
#define B_SZ 2
#define NROW (B_SZ * L_TOT)
#define CHUNK 32
#define NCH (L_TOT / CHUNK)      // 512

static constexpr size_t SLOT_XD  = (size_t)NROW * 64;           // xd (u), later y, per-dir
static constexpr size_t SLOT_DBC = (size_t)NROW * 20;           // dtr(4)+B(8)+C(8) per-dir
static constexpr size_t SLOT_SDT = (size_t)B_SZ * 64 * NCH;     // sum(dt), layout [b][d][ch]
static constexpr size_t SLOT_HC  = (size_t)B_SZ * NCH * 64 * 8; // chunk h, layout [b][ch][d][n]

// scan-position s -> original sequence index l (involution; verified rounds 1-2).
__device__ __forceinline__ int tau_map(int dir, int s) {
  int j = (dir & 1) ? (L_TOT - 1 - s) : s;
  if (dir >= 2) j = ((j & 127) << 7) | (j >> 7);   // transpose of 128x128
  return j;
}
__device__ __forceinline__ float silu_f(float x) { return x / (1.f + __expf(-x)); }
__device__ __forceinline__ float softplus_f(float x) {
  return fmaxf(x, 0.f) + __logf(1.f + __expf(-fabsf(x)));
}

// -------- A: LayerNorm + in_proj. 1-wave blocks, thread=row, xr[64] in VGPRs, ----------
// -------- W via batched scalar loads. blockIdx.y picks x-half / z-half.       ----------
__global__ void __launch_bounds__(64, 2)
k_ln_inproj(const float* __restrict__ inp, const float* __restrict__ lng,
            const float* __restrict__ lnb, const float* __restrict__ W,
            float* __restrict__ xout, float* __restrict__ zout) {
  __shared__ float so[64 * 65];        // output staging for coalesced store
  const int lane = threadIdx.x;        // row l within tile
  const int jh = blockIdx.y;           // 0 -> x half, 1 -> z half
  const int blk = blockIdx.x;          // 512
  const int b = blk >> 8;
  const int l0 = (blk & 255) << 6;
  const float* ip = inp + (size_t)b * 64 * L_TOT + l0 + lane;   // lanes contiguous along l
  float xr[64];
  float m = 0.f;
#pragma unroll
  for (int c = 0; c < 64; ++c) { float v = ip[(size_t)c * L_TOT]; xr[c] = v; m += v; }
  m *= 0.015625f;
  float var = 0.f;
#pragma unroll
  for (int c = 0; c < 64; ++c) { float dv = xr[c] - m; var += dv * dv; }
  var *= 0.015625f;
  const float rstd = rsqrtf(var + 1e-5f);
#pragma unroll
  for (int c = 0; c < 64; ++c) xr[c] = (xr[c] - m) * rstd * lng[c] + lnb[c];
  const float* Wp = W + (size_t)(jh << 6) * 64;   // 64 rows of this half
#pragma unroll 1
  for (int j = 0; j < 64; ++j) {
    float acc = 0.f;
#pragma unroll
    for (int c = 0; c < 64; ++c) acc = fmaf(xr[c], Wp[j * 64 + c], acc);  // W: s_loads
    so[lane * 65 + j] = acc;
  }
  __syncthreads();
  float* op = (jh ? zout : xout) + ((size_t)b * L_TOT + l0) * 64;
#pragma unroll 1
  for (int r = 0; r < 64; ++r)
    op[(size_t)r * 64 + lane] = so[r * 65 + lane];   // coalesced
}

// ------------- B: gather + causal conv(4) + SiLU fused with xproj (20 outs) -------------
__global__ void __launch_bounds__(256, 4)
k_convproj(const float* __restrict__ xbuf, const float* __restrict__ cw,
           const float* __restrict__ cb, const float* __restrict__ xpw,
           float* __restrict__ xd_base, float* __restrict__ dbc_base,
           int dir_base) {
  __shared__ float xt[64 * 65];
  __shared__ float dbl[64 * 20];
  const int t = threadIdx.x;           // 256
  const int slot = blockIdx.y;
  const int dir = dir_base + slot;
  const int blk = blockIdx.x;          // 512
  const int b = blk >> 8;
  const int s0 = (blk & 255) << 6;
  const int lane = t & 63;             // channel
  const int w = t >> 6;
  float wk[4];
#pragma unroll
  for (int k = 0; k < 4; ++k) wk[k] = cw[(dir * 64 + lane) * 4 + k];
  const float bconv = cb[dir * 64 + lane];
  float* xdp = xd_base + (size_t)slot * SLOT_XD + ((size_t)b * L_TOT + s0) * 64;
  const float* xb = xbuf + (size_t)b * L_TOT * 64;
#pragma unroll 1
  for (int rr = 0; rr < 16; ++rr) {
    const int r = rr * 4 + w;
    const int s = s0 + r;
    float acc = bconv;
#pragma unroll
    for (int k = 0; k < 4; ++k) {
      int j = s - 3 + k;
      if (j >= 0) {
        int l = tau_map(dir, j);
        acc += wk[k] * xb[(size_t)l * 64 + lane];
      }
    }
    acc = silu_f(acc);
    xt[r * 65 + lane] = acc;
    xdp[(size_t)r * 64 + lane] = acc;
  }
  __syncthreads();
  {  // xproj: wave g computes j = 5g..5g+4 for all 64 rows
    const int g = w;
    const int srow = lane;
    float acc5[5] = {0.f, 0.f, 0.f, 0.f, 0.f};
    const float* wp = xpw + ((size_t)dir * 20 + g * 5) * 64;
#pragma unroll 1
    for (int c = 0; c < 64; ++c) {
      float xv = xt[srow * 65 + c];
#pragma unroll
      for (int jj = 0; jj < 5; ++jj) acc5[jj] += xv * wp[jj * 64 + c];
    }
#pragma unroll
    for (int jj = 0; jj < 5; ++jj) dbl[srow * 20 + g * 5 + jj] = acc5[jj];
  }
  __syncthreads();
  float* dbp = dbc_base + (size_t)slot * SLOT_DBC + ((size_t)b * L_TOT + s0) * 20;
#pragma unroll 1
  for (int i = t; i < 1280; i += 256) dbp[i] = dbl[i];
}

// ------- S1: chunk-local scan, 4 chunk-waves/block, dbc staged in LDS -------
__global__ void __launch_bounds__(256, 4)
k_scan1(const float* __restrict__ xd_base, const float* __restrict__ dbc_base,
        const float* __restrict__ alog, const float* __restrict__ dtw,
        const float* __restrict__ dtbias,
        float* __restrict__ hcb, float* __restrict__ sdtb, int dir_base) {
  __shared__ float rpl[4 * CHUNK * 20];   // 10 KB
  const int t = threadIdx.x;              // 256
  const int w = t >> 6;
  const int d = t & 63;
  const int ch = blockIdx.x * 4 + w;
  const int slot = blockIdx.y;
  const int dir = dir_base + slot;
  const int b = blockIdx.z;
  const float* rblk = dbc_base + (size_t)slot * SLOT_DBC +
                      ((size_t)b * L_TOT + (size_t)blockIdx.x * 4 * CHUNK) * 20;
#pragma unroll 1
  for (int i = t; i < 4 * CHUNK * 20; i += 256) rpl[i] = rblk[i];
  __syncthreads();
  const float* rp = rpl + w * CHUNK * 20;
  float a[8];
#pragma unroll
  for (int n = 0; n < 8; ++n) a[n] = -__expf(alog[((size_t)dir * 64 + d) * 8 + n]);
  float wdt[4];
#pragma unroll
  for (int r = 0; r < 4; ++r) wdt[r] = dtw[((size_t)dir * 64 + d) * 4 + r];
  const float bia = dtbias[dir * 64 + d];
  const float* up = xd_base + (size_t)slot * SLOT_XD + ((size_t)b * L_TOT + ch * CHUNK) * 64;
  float h[8] = {0,0,0,0,0,0,0,0};
  float sdt = 0.f;
#pragma unroll 4
  for (int s = 0; s < CHUNK; ++s) {
    float u = up[s * 64 + d];
    float dt = bia;
#pragma unroll
    for (int r = 0; r < 4; ++r) dt = fmaf(rp[s * 20 + r], wdt[r], dt);
    dt = softplus_f(dt);
    sdt += dt;
    float du = dt * u;
#pragma unroll
    for (int n = 0; n < 8; ++n)
      h[n] = fmaf(__expf(dt * a[n]), h[n], du * rp[s * 20 + 4 + n]);
  }
  sdtb[(size_t)slot * SLOT_SDT + (((size_t)b * 64 + d) * NCH) + ch] = sdt;
  float* hp = hcb + (size_t)slot * SLOT_HC + (((size_t)b * NCH + ch) * 64 + d) * 8;
#pragma unroll
  for (int n = 0; n < 8; ++n) hp[n] = h[n];
}

// ---- S2: parallel chunk stitch (Hillis-Steele over 512 chunks), exclusive in-place ----
__global__ void k_scan2(float* __restrict__ hcb, const float* __restrict__ sdtb,
                        const float* __restrict__ alog, int dir_base) {
  const int t = threadIdx.x;           // 512 = chunk index
  const int d = blockIdx.x >> 3;
  const int n = blockIdx.x & 7;
  const int slot = blockIdx.y;
  const int dir = dir_base + slot;
  const int b = blockIdx.z;
  const float a = -__expf(alog[((size_t)dir * 64 + d) * 8 + n]);
  float* hcp = hcb + (size_t)slot * SLOT_HC + (size_t)b * NCH * 512;
  const float* sdp = sdtb + (size_t)slot * SLOT_SDT + ((size_t)b * 64 + d) * NCH;
  float e = __expf(a * sdp[t]);                       // coalesced
  float v = hcp[((size_t)t * 64 + d) * 8 + n];
  __shared__ float sE[NCH], sV[NCH];
  sE[t] = e; sV[t] = v;
  __syncthreads();
#pragma unroll
  for (int off = 1; off < NCH; off <<= 1) {
    float pe = 1.f, pv = 0.f;
    if (t >= off) { pe = sE[t - off]; pv = sV[t - off]; }
    __syncthreads();
    v = fmaf(e, pv, v);     // compose: prev then self
    e = e * pe;
    sE[t] = e; sV[t] = v;
    __syncthreads();
  }
  const float hs = (t == 0) ? 0.f : sV[t - 1];   // exclusive = h_start for chunk t
  hcp[((size_t)t * 64 + d) * 8 + n] = hs;
}

// ---- S3: final scan with h_start; y = C.h + u*D; in-place over xd (or scatter-add) ----
__global__ void __launch_bounds__(256, 4)
k_scan3(const float* xd_in, const float* __restrict__ dbc_base,
        const float* __restrict__ hcb, const float* __restrict__ alog,
        const float* __restrict__ dtw, const float* __restrict__ dtbias,
        const float* __restrict__ dsk, float* y_base,
        int dir_base, int scatter) {
  __shared__ float rpl[4 * CHUNK * 20];
  const int t = threadIdx.x;              // 256
  const int w = t >> 6;
  const int d = t & 63;
  const int ch = blockIdx.x * 4 + w;
  const int slot = blockIdx.y;
  const int dir = dir_base + slot;
  const int b = blockIdx.z;
  const float* rblk = dbc_base + (size_t)slot * SLOT_DBC +
                      ((size_t)b * L_TOT + (size_t)blockIdx.x * 4 * CHUNK) * 20;
#pragma unroll 1
  for (int i = t; i < 4 * CHUNK * 20; i += 256) rpl[i] = rblk[i];
  __syncthreads();
  const float* rp = rpl + w * CHUNK * 20;
  float a[8];
#pragma unroll
  for (int n = 0; n < 8; ++n) a[n] = -__expf(alog[((size_t)dir * 64 + d) * 8 + n]);
  float wdt[4];
#pragma unroll
  for (int r = 0; r < 4; ++r) wdt[r] = dtw[((size_t)dir * 64 + d) * 4 + r];
  const float bia = dtbias[dir * 64 + d];
  const float Dv = dsk[dir * 64 + d];
  const float* up = xd_in + (size_t)slot * SLOT_XD + ((size_t)b * L_TOT + ch * CHUNK) * 64;
  const float* hsp = hcb + (size_t)slot * SLOT_HC + (((size_t)b * NCH + ch) * 64 + d) * 8;
  float h[8];
#pragma unroll
  for (int n = 0; n < 8; ++n) h[n] = hsp[n];
  const int sbase = ch * CHUNK;
#pragma unroll 4
  for (int s = 0; s < CHUNK; ++s) {
    float u = up[s * 64 + d];
    float dt = bia;
#pragma unroll
    for (int r = 0; r < 4; ++r) dt = fmaf(rp[s * 20 + r], wdt[r], dt);
    dt = softplus_f(dt);
    float du = dt * u;
    float y = u * Dv;
#pragma unroll
    for (int n = 0; n < 8; ++n) {
      h[n] = fmaf(__expf(dt * a[n]), h[n], du * rp[s * 20 + 4 + n]);
      y = fmaf(rp[s * 20 + 12 + n], h[n], y);
    }
    if (scatter) {
      int l = tau_map(dir, sbase + s);
      float* yp = y_base + ((size_t)b * L_TOT + l) * 64 + d;
      *yp += y;                      // dirs serialized on the stream in this mode
    } else {
      y_base[(size_t)slot * SLOT_XD + ((size_t)b * L_TOT + sbase + s) * 64 + d] = y;
    }
  }
}

// ------- F: gather(sum over dirs) + /4 + LN + *silu(z) + out_proj + residual -------
// 1-wave blocks, thread=row, yr[64] in VGPRs, OW via batched scalar loads.
__global__ void __launch_bounds__(64, 2)
k_final(const float* __restrict__ ybase, const float* __restrict__ zbuf,
        const float* __restrict__ ong, const float* __restrict__ onb,
        const float* __restrict__ OW, const float* __restrict__ inp,
        float* __restrict__ out, int gather) {
  __shared__ float ty[64 * 65];
  __shared__ float tz[64 * 65];
  const int lane = threadIdx.x;        // load: channel; compute: row
  const int blk = blockIdx.x;
  const int b = blk >> 8;
  const int l0 = (blk & 255) << 6;
#pragma unroll 1
  for (int r = 0; r < 64; ++r) {
    const int l = l0 + r;
    float acc;
    if (gather) {
      acc = 0.f;
#pragma unroll
      for (int dir = 0; dir < 4; ++dir) {
        int s = tau_map(dir, l);
        acc += ybase[(size_t)dir * SLOT_XD + ((size_t)b * L_TOT + s) * 64 + lane];
      }
    } else {
      acc = ybase[((size_t)b * L_TOT + l) * 64 + lane];
    }
    ty[r * 65 + lane] = acc;
    tz[r * 65 + lane] = zbuf[((size_t)b * L_TOT + l) * 64 + lane];
  }
  __syncthreads();
  float yr[64];   // row = lane
  float m = 0.f;
#pragma unroll
  for (int c = 0; c < 64; ++c) { float v = ty[lane * 65 + c] * 0.25f; yr[c] = v; m += v; }
  m *= 0.015625f;
  float var = 0.f;
#pragma unroll
  for (int c = 0; c < 64; ++c) { float dv = yr[c] - m; var += dv * dv; }
  var *= 0.015625f;
  const float rstd = rsqrtf(var + 1e-5f);
#pragma unroll
  for (int c = 0; c < 64; ++c) {
    float yv = (yr[c] - m) * rstd * ong[c] + onb[c];
    yr[c] = yv * silu_f(tz[lane * 65 + c]);
  }
  __syncthreads();   // ty free for restaging
#pragma unroll 1
  for (int j = 0; j < 64; ++j) {
    float acc = 0.f;
#pragma unroll
    for (int c = 0; c < 64; ++c) acc = fmaf(yr[c], OW[j * 64 + c], acc);  // s_loads
    ty[lane * 65 + j] = acc;
  }
  __syncthreads();
#pragma unroll 1
  for (int j = 0; j < 64; ++j) {
    size_t o = ((size_t)b * 64 + j) * L_TOT + l0 + lane;
    out[o] = ty[lane * 65 + j] + inp[o];   // wait: need value at (row=lane? no)
  }
}

extern "C" void kernel_launch(void* const* d_in, const int* in_sizes, int n_in,
                              void* d_out, int out_size, void* d_ws, size_t ws_size,
                              hipStream_t stream) {
  const float* inp    = (const float*)d_in[0];
  const float* lng    = (const float*)d_in[1];
  const float* lnb    = (const float*)d_in[2];
  const float* ipw    = (const float*)d_in[3];
  const float* cw     = (const float*)d_in[4];
  const float* cb     = (const float*)d_in[5];
  const float* xpw    = (const float*)d_in[6];
  const float* dtw    = (const float*)d_in[7];
  const float* dtbias = (const float*)d_in[8];
  const float* alog   = (const float*)d_in[9];
  const float* dsk    = (const float*)d_in[10];
  const float* ong    = (const float*)d_in[11];
  const float* onb    = (const float*)d_in[12];
  const float* opw    = (const float*)d_in[13];
  float* out = (float*)d_out;
  float* ws = (float*)d_ws;

  // batched layout: hc aliases xbuf (dead after convproj); 4*SLOT_HC == SLOT_XD
  const size_t need_batched = (6 * SLOT_XD + 4 * SLOT_DBC + 4 * SLOT_SDT) * sizeof(float);

  if (ws_size >= need_batched) {
    size_t off = 0;
    float* xbuf = ws + off; off += SLOT_XD;          // also hc after convproj
    float* zbuf = ws + off; off += SLOT_XD;
    float* xd   = ws + off; off += 4 * SLOT_XD;
    float* dbc  = ws + off; off += 4 * SLOT_DBC;
    float* sdt  = ws + off; off += 4 * SLOT_SDT;
    float* hc   = xbuf;

    k_ln_inproj<<<dim3(512, 2), 64, 0, stream>>>(inp, lng, lnb, ipw, xbuf, zbuf);
    k_convproj<<<dim3(512, 4), 256, 0, stream>>>(xbuf, cw, cb, xpw, xd, dbc, 0);
    k_scan1<<<dim3(NCH / 4, 4, B_SZ), 256, 0, stream>>>(xd, dbc, alog, dtw, dtbias, hc, sdt, 0);
    k_scan2<<<dim3(512, 4, B_SZ), NCH, 0, stream>>>(hc, sdt, alog, 0);
    k_scan3<<<dim3(NCH / 4, 4, B_SZ), 256, 0, stream>>>(xd, dbc, hc, alog, dtw, dtbias, dsk,
                                                        xd, 0, 0);
    k_final<<<dim3(512), 64, 0, stream>>>(xd, zbuf, ong, onb, opw, inp, out, 1);
  } else {
    size_t off = 0;
    float* xbuf = ws + off; off += SLOT_XD;
    float* zbuf = ws + off; off += SLOT_XD;
    float* ysum = ws + off; off += SLOT_XD;
    float* xd   = ws + off; off += SLOT_XD;
    float* dbc  = ws + off; off += SLOT_DBC;
    float* sdt  = ws + off; off += SLOT_SDT;
    float* hc   = ws + off; off += SLOT_HC;

    hipMemsetAsync(ysum, 0, SLOT_XD * sizeof(float), stream);
    k_ln_inproj<<<dim3(512, 2), 64, 0, stream>>>(inp, lng, lnb, ipw, xbuf, zbuf);
    for (int d2 = 0; d2 < 4; ++d2) {
      k_convproj<<<dim3(512, 1), 256, 0, stream>>>(xbuf, cw, cb, xpw, xd, dbc, d2);
      k_scan1<<<dim3(NCH / 4, 1, B_SZ), 256, 0, stream>>>(xd, dbc, alog, dtw, dtbias, hc, sdt, d2);
      k_scan2<<<dim3(512, 1, B_SZ), NCH, 0, stream>>>(hc, sdt, alog, d2);
      k_scan3<<<dim3(NCH / 4, 1, B_SZ), 256, 0, stream>>>(xd, dbc, hc, alog, dtw, dtbias, dsk,
                                                          ysum, d2, 1);
    }
    k_final<<<dim3(512), 64, 0, stream>>>(ysum, zbuf, ong, onb, opw, inp, out, 0);
  }
}

// Round 6
// 192.379 us; speedup vs baseline: 2.3760x; 1.5107x over previous
//
#include <hip/hip_runtime.h>
#include <hip/hip_bf16.h>
#include <cstdint>
#include <cstddef>

#define L_TOT 16384
#define B_SZ 2
#define NROW (B_SZ * L_TOT)
#define CHUNK 32
#define NCH (L_TOT / CHUNK)      // 512

static constexpr size_t SLOT_XD  = (size_t)NROW * 64;           // xd (u), later y, per-dir
static constexpr size_t SLOT_DBC = (size_t)NROW * 20;           // dtr(4)+B(8)+C(8) per-dir
static constexpr size_t SLOT_SDT = (size_t)B_SZ * 64 * NCH;     // sum(dt), layout [b][d][ch]
static constexpr size_t SLOT_HC  = (size_t)B_SZ * NCH * 64 * 8; // chunk h, layout [b][ch][d][n]

// scan-position s -> original sequence index l (involution; verified rounds 1-2).
__device__ __forceinline__ int tau_map(int dir, int s) {
  int j = (dir & 1) ? (L_TOT - 1 - s) : s;
  if (dir >= 2) j = ((j & 127) << 7) | (j >> 7);   // transpose of 128x128
  return j;
}
__device__ __forceinline__ float silu_f(float x) { return x / (1.f + __expf(-x)); }
__device__ __forceinline__ float softplus_f(float x) {
  return fmaxf(x, 0.f) + __logf(1.f + __expf(-fabsf(x)));
}

// ---- A: LN + in_proj as LDS-tiled GEMM. 256 thr, 4x8 register sub-tile per thread. ----
__global__ void __launch_bounds__(256)
k_ln_inproj(const float* __restrict__ inp, const float* __restrict__ lng,
            const float* __restrict__ lnb, const float* __restrict__ W,
            float* __restrict__ xout, float* __restrict__ zout) {
  __shared__ float xt[64 * 65];        // input tile [l][c], pad 65 (conflict-free)
  __shared__ float wrk[8448];          // stats(640) -> W[128][65] -> so[64][132]
  const int t = threadIdx.x;
  const int lane = t & 63;
  const int w = t >> 6;
  const int b = blockIdx.x >> 8;
  const int l0 = (blockIdx.x & 255) << 6;
  // load tile (coalesced along l): xt[l][c]
  const float* ip = inp + (size_t)b * 64 * L_TOT + l0 + lane;
#pragma unroll 4
  for (int cc = 0; cc < 16; ++cc) {
    int c = cc * 4 + w;
    xt[lane * 65 + c] = ip[(size_t)c * L_TOT];
  }
  __syncthreads();
  // LN stats: row = lane, quarter = w
  {
    float s1 = 0.f, s2 = 0.f;
    const int c0 = w * 16;
#pragma unroll
    for (int cc = 0; cc < 16; ++cc) {
      float v = xt[lane * 65 + c0 + cc];
      s1 += v; s2 = fmaf(v, v, s2);
    }
    wrk[w * 64 + lane] = s1;
    wrk[256 + w * 64 + lane] = s2;
  }
  __syncthreads();
  if (t < 64) {
    float s1 = wrk[t] + wrk[64 + t] + wrk[128 + t] + wrk[192 + t];
    float s2 = wrk[256 + t] + wrk[320 + t] + wrk[384 + t] + wrk[448 + t];
    float m = s1 * 0.015625f;
    float var = s2 * 0.015625f - m * m;
    wrk[512 + t] = m;
    wrk[576 + t] = rsqrtf(var + 1e-5f);
  }
  __syncthreads();
  // normalize in place
  {
    const float mv = wrk[512 + lane], rv = wrk[576 + lane];
#pragma unroll 4
    for (int k = 0; k < 16; ++k) {
      int c = w + 4 * k;
      float g = lng[c], bb = lnb[c];
      float v = xt[lane * 65 + c];
      xt[lane * 65 + c] = (v - mv) * rv * g + bb;
    }
  }
  __syncthreads();
  // stage W [128][65] (overwrites stats region; stats dead)
#pragma unroll 4
  for (int rep = 0; rep < 32; ++rep) {
    int j = rep * 4 + w;
    wrk[j * 65 + lane] = W[(size_t)j * 64 + lane];
  }
  __syncthreads();
  // GEMM: thread = (rg, jg) in wave w; rows r0..r0+3, cols j0..j0+7
  const int rg = lane & 15;
  const int jg = lane >> 4;
  const int j0 = w * 32 + jg * 8;
  const int r0 = rg * 4;
  float acc[4][8] = {};
#pragma unroll 2
  for (int c = 0; c < 64; ++c) {
    float xv[4], wv[8];
#pragma unroll
    for (int i = 0; i < 4; ++i) xv[i] = xt[(r0 + i) * 65 + c];
#pragma unroll
    for (int jj = 0; jj < 8; ++jj) wv[jj] = wrk[(j0 + jj) * 65 + c];
#pragma unroll
    for (int i = 0; i < 4; ++i)
#pragma unroll
      for (int jj = 0; jj < 8; ++jj) acc[i][jj] = fmaf(xv[i], wv[jj], acc[i][jj]);
  }
  __syncthreads();
  // stage outputs so[r][132] for coalesced store
#pragma unroll
  for (int i = 0; i < 4; ++i)
#pragma unroll
    for (int jj = 0; jj < 8; ++jj) wrk[(r0 + i) * 132 + j0 + jj] = acc[i][jj];
  __syncthreads();
  float* xo = xout + ((size_t)b * L_TOT + l0) * 64;
  float* zo = zout + ((size_t)b * L_TOT + l0) * 64;
#pragma unroll 4
  for (int rep = 0; rep < 16; ++rep) {
    int r = rep * 4 + w;
    xo[(size_t)r * 64 + lane] = wrk[r * 132 + lane];
    zo[(size_t)r * 64 + lane] = wrk[r * 132 + 64 + lane];
  }
}

// ------------- B: gather + causal conv(4) + SiLU fused with xproj (20 outs) -------------
__global__ void __launch_bounds__(256, 4)
k_convproj(const float* __restrict__ xbuf, const float* __restrict__ cw,
           const float* __restrict__ cb, const float* __restrict__ xpw,
           float* __restrict__ xd_base, float* __restrict__ dbc_base,
           int dir_base) {
  __shared__ float xt[64 * 65];
  __shared__ float dbl[64 * 20];
  const int t = threadIdx.x;           // 256
  const int slot = blockIdx.y;
  const int dir = dir_base + slot;
  const int blk = blockIdx.x;          // 512
  const int b = blk >> 8;
  const int s0 = (blk & 255) << 6;
  const int lane = t & 63;             // channel
  const int w = t >> 6;
  float wk[4];
#pragma unroll
  for (int k = 0; k < 4; ++k) wk[k] = cw[(dir * 64 + lane) * 4 + k];
  const float bconv = cb[dir * 64 + lane];
  float* xdp = xd_base + (size_t)slot * SLOT_XD + ((size_t)b * L_TOT + s0) * 64;
  const float* xb = xbuf + (size_t)b * L_TOT * 64;
#pragma unroll 1
  for (int rr = 0; rr < 16; ++rr) {
    const int r = rr * 4 + w;
    const int s = s0 + r;
    float acc = bconv;
#pragma unroll
    for (int k = 0; k < 4; ++k) {
      int j = s - 3 + k;
      if (j >= 0) {
        int l = tau_map(dir, j);
        acc += wk[k] * xb[(size_t)l * 64 + lane];
      }
    }
    acc = silu_f(acc);
    xt[r * 65 + lane] = acc;
    xdp[(size_t)r * 64 + lane] = acc;
  }
  __syncthreads();
  {  // xproj: wave g computes j = 5g..5g+4 for all 64 rows
    const int g = w;
    const int srow = lane;
    float acc5[5] = {0.f, 0.f, 0.f, 0.f, 0.f};
    const float* wp = xpw + ((size_t)dir * 20 + g * 5) * 64;
#pragma unroll 1
    for (int c = 0; c < 64; ++c) {
      float xv = xt[srow * 65 + c];
#pragma unroll
      for (int jj = 0; jj < 5; ++jj) acc5[jj] += xv * wp[jj * 64 + c];
    }
#pragma unroll
    for (int jj = 0; jj < 5; ++jj) dbl[srow * 20 + g * 5 + jj] = acc5[jj];
  }
  __syncthreads();
  float* dbp = dbc_base + (size_t)slot * SLOT_DBC + ((size_t)b * L_TOT + s0) * 20;
#pragma unroll 1
  for (int i = t; i < 1280; i += 256) dbp[i] = dbl[i];
}

// ------- S1: chunk-local scan, 4 chunk-waves/block, dbc staged in LDS -------
__global__ void __launch_bounds__(256, 4)
k_scan1(const float* __restrict__ xd_base, const float* __restrict__ dbc_base,
        const float* __restrict__ alog, const float* __restrict__ dtw,
        const float* __restrict__ dtbias,
        float* __restrict__ hcb, float* __restrict__ sdtb, int dir_base) {
  __shared__ float rpl[4 * CHUNK * 20];   // 10 KB
  const int t = threadIdx.x;              // 256
  const int w = t >> 6;
  const int d = t & 63;
  const int ch = blockIdx.x * 4 + w;
  const int slot = blockIdx.y;
  const int dir = dir_base + slot;
  const int b = blockIdx.z;
  const float* rblk = dbc_base + (size_t)slot * SLOT_DBC +
                      ((size_t)b * L_TOT + (size_t)blockIdx.x * 4 * CHUNK) * 20;
#pragma unroll 1
  for (int i = t; i < 4 * CHUNK * 20; i += 256) rpl[i] = rblk[i];
  __syncthreads();
  const float* rp = rpl + w * CHUNK * 20;
  float a[8];
#pragma unroll
  for (int n = 0; n < 8; ++n) a[n] = -__expf(alog[((size_t)dir * 64 + d) * 8 + n]);
  float wdt[4];
#pragma unroll
  for (int r = 0; r < 4; ++r) wdt[r] = dtw[((size_t)dir * 64 + d) * 4 + r];
  const float bia = dtbias[dir * 64 + d];
  const float* up = xd_base + (size_t)slot * SLOT_XD + ((size_t)b * L_TOT + ch * CHUNK) * 64;
  float h[8] = {0,0,0,0,0,0,0,0};
  float sdt = 0.f;
#pragma unroll 4
  for (int s = 0; s < CHUNK; ++s) {
    float u = up[s * 64 + d];
    float dt = bia;
#pragma unroll
    for (int r = 0; r < 4; ++r) dt = fmaf(rp[s * 20 + r], wdt[r], dt);
    dt = softplus_f(dt);
    sdt += dt;
    float du = dt * u;
#pragma unroll
    for (int n = 0; n < 8; ++n)
      h[n] = fmaf(__expf(dt * a[n]), h[n], du * rp[s * 20 + 4 + n]);
  }
  sdtb[(size_t)slot * SLOT_SDT + (((size_t)b * 64 + d) * NCH) + ch] = sdt;
  float* hp = hcb + (size_t)slot * SLOT_HC + (((size_t)b * NCH + ch) * 64 + d) * 8;
#pragma unroll
  for (int n = 0; n < 8; ++n) hp[n] = h[n];
}

// ---- S2: parallel chunk stitch (Hillis-Steele over 512 chunks), exclusive in-place ----
__global__ void k_scan2(float* __restrict__ hcb, const float* __restrict__ sdtb,
                        const float* __restrict__ alog, int dir_base) {
  const int t = threadIdx.x;           // 512 = chunk index
  const int d = blockIdx.x >> 3;
  const int n = blockIdx.x & 7;
  const int slot = blockIdx.y;
  const int dir = dir_base + slot;
  const int b = blockIdx.z;
  const float a = -__expf(alog[((size_t)dir * 64 + d) * 8 + n]);
  float* hcp = hcb + (size_t)slot * SLOT_HC + (size_t)b * NCH * 512;
  const float* sdp = sdtb + (size_t)slot * SLOT_SDT + ((size_t)b * 64 + d) * NCH;
  float e = __expf(a * sdp[t]);                       // coalesced
  float v = hcp[((size_t)t * 64 + d) * 8 + n];
  __shared__ float sE[NCH], sV[NCH];
  sE[t] = e; sV[t] = v;
  __syncthreads();
#pragma unroll
  for (int off = 1; off < NCH; off <<= 1) {
    float pe = 1.f, pv = 0.f;
    if (t >= off) { pe = sE[t - off]; pv = sV[t - off]; }
    __syncthreads();
    v = fmaf(e, pv, v);     // compose: prev then self
    e = e * pe;
    sE[t] = e; sV[t] = v;
    __syncthreads();
  }
  const float hs = (t == 0) ? 0.f : sV[t - 1];   // exclusive = h_start for chunk t
  hcp[((size_t)t * 64 + d) * 8 + n] = hs;
}

// ---- S3: final scan with h_start; y = C.h + u*D; in-place over xd (or scatter-add) ----
__global__ void __launch_bounds__(256, 4)
k_scan3(const float* xd_in, const float* __restrict__ dbc_base,
        const float* __restrict__ hcb, const float* __restrict__ alog,
        const float* __restrict__ dtw, const float* __restrict__ dtbias,
        const float* __restrict__ dsk, float* y_base,
        int dir_base, int scatter) {
  __shared__ float rpl[4 * CHUNK * 20];
  const int t = threadIdx.x;              // 256
  const int w = t >> 6;
  const int d = t & 63;
  const int ch = blockIdx.x * 4 + w;
  const int slot = blockIdx.y;
  const int dir = dir_base + slot;
  const int b = blockIdx.z;
  const float* rblk = dbc_base + (size_t)slot * SLOT_DBC +
                      ((size_t)b * L_TOT + (size_t)blockIdx.x * 4 * CHUNK) * 20;
#pragma unroll 1
  for (int i = t; i < 4 * CHUNK * 20; i += 256) rpl[i] = rblk[i];
  __syncthreads();
  const float* rp = rpl + w * CHUNK * 20;
  float a[8];
#pragma unroll
  for (int n = 0; n < 8; ++n) a[n] = -__expf(alog[((size_t)dir * 64 + d) * 8 + n]);
  float wdt[4];
#pragma unroll
  for (int r = 0; r < 4; ++r) wdt[r] = dtw[((size_t)dir * 64 + d) * 4 + r];
  const float bia = dtbias[dir * 64 + d];
  const float Dv = dsk[dir * 64 + d];
  const float* up = xd_in + (size_t)slot * SLOT_XD + ((size_t)b * L_TOT + ch * CHUNK) * 64;
  const float* hsp = hcb + (size_t)slot * SLOT_HC + (((size_t)b * NCH + ch) * 64 + d) * 8;
  float h[8];
#pragma unroll
  for (int n = 0; n < 8; ++n) h[n] = hsp[n];
  const int sbase = ch * CHUNK;
#pragma unroll 4
  for (int s = 0; s < CHUNK; ++s) {
    float u = up[s * 64 + d];
    float dt = bia;
#pragma unroll
    for (int r = 0; r < 4; ++r) dt = fmaf(rp[s * 20 + r], wdt[r], dt);
    dt = softplus_f(dt);
    float du = dt * u;
    float y = u * Dv;
#pragma unroll
    for (int n = 0; n < 8; ++n) {
      h[n] = fmaf(__expf(dt * a[n]), h[n], du * rp[s * 20 + 4 + n]);
      y = fmaf(rp[s * 20 + 12 + n], h[n], y);
    }
    if (scatter) {
      int l = tau_map(dir, sbase + s);
      float* yp = y_base + ((size_t)b * L_TOT + l) * 64 + d;
      *yp += y;                      // dirs serialized on the stream in this mode
    } else {
      y_base[(size_t)slot * SLOT_XD + ((size_t)b * L_TOT + sbase + s) * 64 + d] = y;
    }
  }
}

// ---- F: gather + /4 + LN + *silu(z) + out_proj + residual as LDS-tiled GEMM ----
__global__ void __launch_bounds__(256)
k_final(const float* __restrict__ ybase, const float* __restrict__ zbuf,
        const float* __restrict__ ong, const float* __restrict__ onb,
        const float* __restrict__ OW, const float* __restrict__ inp,
        float* __restrict__ out, int gather) {
  __shared__ float xt[64 * 65];        // y tile [l][c] -> normalized -> so[j][65]
  __shared__ float tzw[64 * 65];       // z tile [l][c] -> W[64][65]
  __shared__ float st[640];            // LN stats
  const int t = threadIdx.x;
  const int lane = t & 63;
  const int w = t >> 6;
  const int b = blockIdx.x >> 8;
  const int l0 = (blockIdx.x & 255) << 6;
  // gather + z load (coalesced: lane = channel)
#pragma unroll 2
  for (int rep = 0; rep < 16; ++rep) {
    int r = rep * 4 + w;
    int l = l0 + r;
    float acc;
    if (gather) {
      acc = 0.f;
#pragma unroll
      for (int dir = 0; dir < 4; ++dir) {
        int s = tau_map(dir, l);
        acc += ybase[(size_t)dir * SLOT_XD + ((size_t)b * L_TOT + s) * 64 + lane];
      }
    } else {
      acc = ybase[((size_t)b * L_TOT + l) * 64 + lane];
    }
    xt[r * 65 + lane] = acc * 0.25f;
    tzw[r * 65 + lane] = zbuf[((size_t)b * L_TOT + l) * 64 + lane];
  }
  __syncthreads();
  {  // LN stats
    float s1 = 0.f, s2 = 0.f;
    const int c0 = w * 16;
#pragma unroll
    for (int cc = 0; cc < 16; ++cc) {
      float v = xt[lane * 65 + c0 + cc];
      s1 += v; s2 = fmaf(v, v, s2);
    }
    st[w * 64 + lane] = s1;
    st[256 + w * 64 + lane] = s2;
  }
  __syncthreads();
  if (t < 64) {
    float s1 = st[t] + st[64 + t] + st[128 + t] + st[192 + t];
    float s2 = st[256 + t] + st[320 + t] + st[384 + t] + st[448 + t];
    float m = s1 * 0.015625f;
    float var = s2 * 0.015625f - m * m;
    st[512 + t] = m;
    st[576 + t] = rsqrtf(var + 1e-5f);
  }
  __syncthreads();
  {  // normalize + silu(z) gate, in place
    const float mv = st[512 + lane], rv = st[576 + lane];
#pragma unroll 4
    for (int k = 0; k < 16; ++k) {
      int c = w + 4 * k;
      float g = ong[c], bb = onb[c];
      float v = xt[lane * 65 + c];
      float zz = tzw[lane * 65 + c];
      xt[lane * 65 + c] = ((v - mv) * rv * g + bb) * silu_f(zz);
    }
  }
  __syncthreads();
  // stage OW [64][65] into tzw (z dead)
#pragma unroll 4
  for (int rep = 0; rep < 16; ++rep) {
    int j = rep * 4 + w;
    tzw[j * 65 + lane] = OW[(size_t)j * 64 + lane];
  }
  __syncthreads();
  // GEMM 4x4 register sub-tile
  const int rg = lane & 15;
  const int jg = lane >> 4;
  const int j0 = w * 16 + jg * 4;
  const int r0 = rg * 4;
  float acc[4][4] = {};
#pragma unroll 2
  for (int c = 0; c < 64; ++c) {
    float xv[4], wv[4];
#pragma unroll
    for (int i = 0; i < 4; ++i) xv[i] = xt[(r0 + i) * 65 + c];
#pragma unroll
    for (int jj = 0; jj < 4; ++jj) wv[jj] = tzw[(j0 + jj) * 65 + c];
#pragma unroll
    for (int i = 0; i < 4; ++i)
#pragma unroll
      for (int jj = 0; jj < 4; ++jj) acc[i][jj] = fmaf(xv[i], wv[jj], acc[i][jj]);
  }
  __syncthreads();
  // so[j][r] into xt region
#pragma unroll
  for (int i = 0; i < 4; ++i)
#pragma unroll
    for (int jj = 0; jj < 4; ++jj) xt[(j0 + jj) * 65 + r0 + i] = acc[i][jj];
  __syncthreads();
  // store + residual (coalesced along l)
#pragma unroll 4
  for (int rep = 0; rep < 16; ++rep) {
    int j = rep * 4 + w;
    size_t o = ((size_t)b * 64 + j) * L_TOT + l0 + lane;
    out[o] = xt[j * 65 + lane] + inp[o];
  }
}

extern "C" void kernel_launch(void* const* d_in, const int* in_sizes, int n_in,
                              void* d_out, int out_size, void* d_ws, size_t ws_size,
                              hipStream_t stream) {
  const float* inp    = (const float*)d_in[0];
  const float* lng    = (const float*)d_in[1];
  const float* lnb    = (const float*)d_in[2];
  const float* ipw    = (const float*)d_in[3];
  const float* cw     = (const float*)d_in[4];
  const float* cb     = (const float*)d_in[5];
  const float* xpw    = (const float*)d_in[6];
  const float* dtw    = (const float*)d_in[7];
  const float* dtbias = (const float*)d_in[8];
  const float* alog   = (const float*)d_in[9];
  const float* dsk    = (const float*)d_in[10];
  const float* ong    = (const float*)d_in[11];
  const float* onb    = (const float*)d_in[12];
  const float* opw    = (const float*)d_in[13];
  float* out = (float*)d_out;
  float* ws = (float*)d_ws;

  // batched layout: hc aliases xbuf (dead after convproj); 4*SLOT_HC == SLOT_XD
  const size_t need_batched = (6 * SLOT_XD + 4 * SLOT_DBC + 4 * SLOT_SDT) * sizeof(float);

  if (ws_size >= need_batched) {
    size_t off = 0;
    float* xbuf = ws + off; off += SLOT_XD;          // also hc after convproj
    float* zbuf = ws + off; off += SLOT_XD;
    float* xd   = ws + off; off += 4 * SLOT_XD;
    float* dbc  = ws + off; off += 4 * SLOT_DBC;
    float* sdt  = ws + off; off += 4 * SLOT_SDT;
    float* hc   = xbuf;

    k_ln_inproj<<<dim3(512), 256, 0, stream>>>(inp, lng, lnb, ipw, xbuf, zbuf);
    k_convproj<<<dim3(512, 4), 256, 0, stream>>>(xbuf, cw, cb, xpw, xd, dbc, 0);
    k_scan1<<<dim3(NCH / 4, 4, B_SZ), 256, 0, stream>>>(xd, dbc, alog, dtw, dtbias, hc, sdt, 0);
    k_scan2<<<dim3(512, 4, B_SZ), NCH, 0, stream>>>(hc, sdt, alog, 0);
    k_scan3<<<dim3(NCH / 4, 4, B_SZ), 256, 0, stream>>>(xd, dbc, hc, alog, dtw, dtbias, dsk,
                                                        xd, 0, 0);
    k_final<<<dim3(512), 256, 0, stream>>>(xd, zbuf, ong, onb, opw, inp, out, 1);
  } else {
    size_t off = 0;
    float* xbuf = ws + off; off += SLOT_XD;
    float* zbuf = ws + off; off += SLOT_XD;
    float* ysum = ws + off; off += SLOT_XD;
    float* xd   = ws + off; off += SLOT_XD;
    float* dbc  = ws + off; off += SLOT_DBC;
    float* sdt  = ws + off; off += SLOT_SDT;
    float* hc   = ws + off; off += SLOT_HC;

    hipMemsetAsync(ysum, 0, SLOT_XD * sizeof(float), stream);
    k_ln_inproj<<<dim3(512), 256, 0, stream>>>(inp, lng, lnb, ipw, xbuf, zbuf);
    for (int d2 = 0; d2 < 4; ++d2) {
      k_convproj<<<dim3(512, 1), 256, 0, stream>>>(xbuf, cw, cb, xpw, xd, dbc, d2);
      k_scan1<<<dim3(NCH / 4, 1, B_SZ), 256, 0, stream>>>(xd, dbc, alog, dtw, dtbias, hc, sdt, d2);
      k_scan2<<<dim3(512, 1, B_SZ), NCH, 0, stream>>>(hc, sdt, alog, d2);
      k_scan3<<<dim3(NCH / 4, 1, B_SZ), 256, 0, stream>>>(xd, dbc, hc, alog, dtw, dtbias, dsk,
                                                          ysum, d2, 1);
    }
    k_final<<<dim3(512), 256, 0, stream>>>(ysum, zbuf, ong, onb, opw, inp, out, 0);
  }
}

// Round 7
// 151.974 us; speedup vs baseline: 3.0077x; 1.2659x over previous
//
#include <hip/hip_runtime.h>
#include <hip/hip_bf16.h>
#include <cstdint>
#include <cstddef>

#define L_TOT 16384
#define B_SZ 2
#define NROW (B_SZ * L_TOT)
#define CHUNK 32
#define NCH (L_TOT / CHUNK)      // 512

static constexpr size_t SLOT_XD  = (size_t)NROW * 64;           // xd (u), later y, per-dir
static constexpr size_t SLOT_DBC = (size_t)NROW * 20;           // dtr(4)+B(8)+C(8) per-dir
static constexpr size_t SLOT_SDT = (size_t)B_SZ * 64 * NCH;     // sum(dt), layout [b][d][ch]
static constexpr size_t SLOT_HC  = (size_t)B_SZ * NCH * 64 * 8; // chunk h, layout [b][ch][d][n]

// scan-position s -> original sequence index l (involution; verified rounds 1-2).
__device__ __forceinline__ int tau_map(int dir, int s) {
  int j = (dir & 1) ? (L_TOT - 1 - s) : s;
  if (dir >= 2) j = ((j & 127) << 7) | (j >> 7);   // transpose of 128x128
  return j;
}
__device__ __forceinline__ float silu_f(float x) { return x / (1.f + __expf(-x)); }
__device__ __forceinline__ float softplus_f(float x) {
  return fmaxf(x, 0.f) + __logf(1.f + __expf(-fabsf(x)));
}

// ---- A: LN + in_proj as LDS-tiled GEMM. 256 thr, 4x8 register sub-tile per thread. ----
__global__ void __launch_bounds__(256)
k_ln_inproj(const float* __restrict__ inp, const float* __restrict__ lng,
            const float* __restrict__ lnb, const float* __restrict__ W,
            float* __restrict__ xout, float* __restrict__ zout) {
  __shared__ float xt[64 * 65];        // input tile [l][c], pad 65 (conflict-free)
  __shared__ float wrk[8448];          // stats(640) -> W[128][65] -> so[64][132]
  const int t = threadIdx.x;
  const int lane = t & 63;
  const int w = t >> 6;
  const int b = blockIdx.x >> 8;
  const int l0 = (blockIdx.x & 255) << 6;
  // load tile (coalesced along l): xt[l][c]
  const float* ip = inp + (size_t)b * 64 * L_TOT + l0 + lane;
#pragma unroll 4
  for (int cc = 0; cc < 16; ++cc) {
    int c = cc * 4 + w;
    xt[lane * 65 + c] = ip[(size_t)c * L_TOT];
  }
  __syncthreads();
  // LN stats: row = lane, quarter = w
  {
    float s1 = 0.f, s2 = 0.f;
    const int c0 = w * 16;
#pragma unroll
    for (int cc = 0; cc < 16; ++cc) {
      float v = xt[lane * 65 + c0 + cc];
      s1 += v; s2 = fmaf(v, v, s2);
    }
    wrk[w * 64 + lane] = s1;
    wrk[256 + w * 64 + lane] = s2;
  }
  __syncthreads();
  if (t < 64) {
    float s1 = wrk[t] + wrk[64 + t] + wrk[128 + t] + wrk[192 + t];
    float s2 = wrk[256 + t] + wrk[320 + t] + wrk[384 + t] + wrk[448 + t];
    float m = s1 * 0.015625f;
    float var = s2 * 0.015625f - m * m;
    wrk[512 + t] = m;
    wrk[576 + t] = rsqrtf(var + 1e-5f);
  }
  __syncthreads();
  // normalize in place
  {
    const float mv = wrk[512 + lane], rv = wrk[576 + lane];
#pragma unroll 4
    for (int k = 0; k < 16; ++k) {
      int c = w + 4 * k;
      float g = lng[c], bb = lnb[c];
      float v = xt[lane * 65 + c];
      xt[lane * 65 + c] = (v - mv) * rv * g + bb;
    }
  }
  __syncthreads();
  // stage W [128][65] (overwrites stats region; stats dead)
#pragma unroll 4
  for (int rep = 0; rep < 32; ++rep) {
    int j = rep * 4 + w;
    wrk[j * 65 + lane] = W[(size_t)j * 64 + lane];
  }
  __syncthreads();
  // GEMM: thread = (rg, jg) in wave w; rows r0..r0+3, cols j0..j0+7
  const int rg = lane & 15;
  const int jg = lane >> 4;
  const int j0 = w * 32 + jg * 8;
  const int r0 = rg * 4;
  float acc[4][8] = {};
#pragma unroll 2
  for (int c = 0; c < 64; ++c) {
    float xv[4], wv[8];
#pragma unroll
    for (int i = 0; i < 4; ++i) xv[i] = xt[(r0 + i) * 65 + c];
#pragma unroll
    for (int jj = 0; jj < 8; ++jj) wv[jj] = wrk[(j0 + jj) * 65 + c];
#pragma unroll
    for (int i = 0; i < 4; ++i)
#pragma unroll
      for (int jj = 0; jj < 8; ++jj) acc[i][jj] = fmaf(xv[i], wv[jj], acc[i][jj]);
  }
  __syncthreads();
  // stage outputs so[r][132] for coalesced store
#pragma unroll
  for (int i = 0; i < 4; ++i)
#pragma unroll
    for (int jj = 0; jj < 8; ++jj) wrk[(r0 + i) * 132 + j0 + jj] = acc[i][jj];
  __syncthreads();
  float* xo = xout + ((size_t)b * L_TOT + l0) * 64;
  float* zo = zout + ((size_t)b * L_TOT + l0) * 64;
#pragma unroll 4
  for (int rep = 0; rep < 16; ++rep) {
    int r = rep * 4 + w;
    xo[(size_t)r * 64 + lane] = wrk[r * 132 + lane];
    zo[(size_t)r * 64 + lane] = wrk[r * 132 + 64 + lane];
  }
}

// ---- B: gather + causal conv(4) + SiLU + xproj, all LDS-staged (round-6 rewrite) ----
// Stage halo'd x tile (67 rows) once -> conv from LDS -> xproj with LDS-resident weights.
__global__ void __launch_bounds__(256)
k_convproj(const float* __restrict__ xbuf, const float* __restrict__ cw,
           const float* __restrict__ cb, const float* __restrict__ xpw,
           float* __restrict__ xd_base, float* __restrict__ dbc_base,
           int dir_base) {
  __shared__ float xh[67 * 65];        // rows i ~ s = s0-3+i; later reused as u tile [64][65]
  __shared__ float wt[20 * 65];        // xproj weights [j][c]
  __shared__ float dbl[64 * 20];
  const int t = threadIdx.x;           // 256
  const int lane = t & 63;             // channel
  const int w = t >> 6;
  const int slot = blockIdx.y;
  const int dir = dir_base + slot;
  const int blk = blockIdx.x;          // 512
  const int b = blk >> 8;
  const int s0 = (blk & 255) << 6;
  const float* xb = xbuf + (size_t)b * L_TOT * 64;
  // stage halo + tile (coalesced row loads; zeros for s<0)
#pragma unroll 1
  for (int i = w; i < 67; i += 4) {
    int s = s0 - 3 + i;
    float v = 0.f;
    if (s >= 0) v = xb[(size_t)tau_map(dir, s) * 64 + lane];
    xh[i * 65 + lane] = v;
  }
  // stage xproj weights (20 rows)
#pragma unroll
  for (int jj = 0; jj < 5; ++jj) {
    int j = jj * 4 + w;
    wt[j * 65 + lane] = xpw[((size_t)dir * 20 + j) * 64 + lane];
  }
  __syncthreads();
  // conv + silu from LDS; u kept in registers; store xd
  float wk[4];
#pragma unroll
  for (int k = 0; k < 4; ++k) wk[k] = cw[(dir * 64 + lane) * 4 + k];
  const float bconv = cb[dir * 64 + lane];
  float u[16];
  float* xdp = xd_base + (size_t)slot * SLOT_XD + ((size_t)b * L_TOT + s0) * 64;
#pragma unroll 4
  for (int rr = 0; rr < 16; ++rr) {
    const int r = rr * 4 + w;
    float acc = bconv;
#pragma unroll
    for (int k = 0; k < 4; ++k) acc = fmaf(wk[k], xh[(r + k) * 65 + lane], acc);
    acc = silu_f(acc);
    u[rr] = acc;
    xdp[(size_t)r * 64 + lane] = acc;
  }
  __syncthreads();   // all conv reads of xh complete
  // write u tile into xh region (now dead): xt[r][c]
  float* xt = xh;
#pragma unroll 4
  for (int rr = 0; rr < 16; ++rr) xt[(rr * 4 + w) * 65 + lane] = u[rr];
  __syncthreads();
  // xproj: wave w computes j = 5w..5w+4 for all 64 rows (row = lane)
  {
    float acc5[5] = {0.f, 0.f, 0.f, 0.f, 0.f};
#pragma unroll 2
    for (int c = 0; c < 64; ++c) {
      float xv = xt[lane * 65 + c];
#pragma unroll
      for (int jj = 0; jj < 5; ++jj)
        acc5[jj] = fmaf(xv, wt[(w * 5 + jj) * 65 + c], acc5[jj]);
    }
#pragma unroll
    for (int jj = 0; jj < 5; ++jj) dbl[lane * 20 + w * 5 + jj] = acc5[jj];
  }
  __syncthreads();
  float* dbp = dbc_base + (size_t)slot * SLOT_DBC + ((size_t)b * L_TOT + s0) * 20;
#pragma unroll
  for (int i = t; i < 1280; i += 256) dbp[i] = dbl[i];
}

// ------- S1: chunk-local scan, 4 chunk-waves/block, dbc staged in LDS -------
__global__ void __launch_bounds__(256, 4)
k_scan1(const float* __restrict__ xd_base, const float* __restrict__ dbc_base,
        const float* __restrict__ alog, const float* __restrict__ dtw,
        const float* __restrict__ dtbias,
        float* __restrict__ hcb, float* __restrict__ sdtb, int dir_base) {
  __shared__ float rpl[4 * CHUNK * 20];   // 10 KB
  const int t = threadIdx.x;              // 256
  const int w = t >> 6;
  const int d = t & 63;
  const int ch = blockIdx.x * 4 + w;
  const int slot = blockIdx.y;
  const int dir = dir_base + slot;
  const int b = blockIdx.z;
  const float* rblk = dbc_base + (size_t)slot * SLOT_DBC +
                      ((size_t)b * L_TOT + (size_t)blockIdx.x * 4 * CHUNK) * 20;
#pragma unroll 1
  for (int i = t; i < 4 * CHUNK * 20; i += 256) rpl[i] = rblk[i];
  __syncthreads();
  const float* rp = rpl + w * CHUNK * 20;
  float a[8];
#pragma unroll
  for (int n = 0; n < 8; ++n) a[n] = -__expf(alog[((size_t)dir * 64 + d) * 8 + n]);
  float wdt[4];
#pragma unroll
  for (int r = 0; r < 4; ++r) wdt[r] = dtw[((size_t)dir * 64 + d) * 4 + r];
  const float bia = dtbias[dir * 64 + d];
  const float* up = xd_base + (size_t)slot * SLOT_XD + ((size_t)b * L_TOT + ch * CHUNK) * 64;
  float h[8] = {0,0,0,0,0,0,0,0};
  float sdt = 0.f;
#pragma unroll 4
  for (int s = 0; s < CHUNK; ++s) {
    float u = up[s * 64 + d];
    float dt = bia;
#pragma unroll
    for (int r = 0; r < 4; ++r) dt = fmaf(rp[s * 20 + r], wdt[r], dt);
    dt = softplus_f(dt);
    sdt += dt;
    float du = dt * u;
#pragma unroll
    for (int n = 0; n < 8; ++n)
      h[n] = fmaf(__expf(dt * a[n]), h[n], du * rp[s * 20 + 4 + n]);
  }
  sdtb[(size_t)slot * SLOT_SDT + (((size_t)b * 64 + d) * NCH) + ch] = sdt;
  float* hp = hcb + (size_t)slot * SLOT_HC + (((size_t)b * NCH + ch) * 64 + d) * 8;
#pragma unroll
  for (int n = 0; n < 8; ++n) hp[n] = h[n];
}

// ---- S2: parallel chunk stitch (Hillis-Steele over 512 chunks), exclusive in-place ----
__global__ void k_scan2(float* __restrict__ hcb, const float* __restrict__ sdtb,
                        const float* __restrict__ alog, int dir_base) {
  const int t = threadIdx.x;           // 512 = chunk index
  const int d = blockIdx.x >> 3;
  const int n = blockIdx.x & 7;
  const int slot = blockIdx.y;
  const int dir = dir_base + slot;
  const int b = blockIdx.z;
  const float a = -__expf(alog[((size_t)dir * 64 + d) * 8 + n]);
  float* hcp = hcb + (size_t)slot * SLOT_HC + (size_t)b * NCH * 512;
  const float* sdp = sdtb + (size_t)slot * SLOT_SDT + ((size_t)b * 64 + d) * NCH;
  float e = __expf(a * sdp[t]);                       // coalesced
  float v = hcp[((size_t)t * 64 + d) * 8 + n];
  __shared__ float sE[NCH], sV[NCH];
  sE[t] = e; sV[t] = v;
  __syncthreads();
#pragma unroll
  for (int off = 1; off < NCH; off <<= 1) {
    float pe = 1.f, pv = 0.f;
    if (t >= off) { pe = sE[t - off]; pv = sV[t - off]; }
    __syncthreads();
    v = fmaf(e, pv, v);     // compose: prev then self
    e = e * pe;
    sE[t] = e; sV[t] = v;
    __syncthreads();
  }
  const float hs = (t == 0) ? 0.f : sV[t - 1];   // exclusive = h_start for chunk t
  hcp[((size_t)t * 64 + d) * 8 + n] = hs;
}

// ---- S3: final scan with h_start; y = C.h + u*D; in-place over xd (or scatter-add) ----
__global__ void __launch_bounds__(256, 4)
k_scan3(const float* xd_in, const float* __restrict__ dbc_base,
        const float* __restrict__ hcb, const float* __restrict__ alog,
        const float* __restrict__ dtw, const float* __restrict__ dtbias,
        const float* __restrict__ dsk, float* y_base,
        int dir_base, int scatter) {
  __shared__ float rpl[4 * CHUNK * 20];
  const int t = threadIdx.x;              // 256
  const int w = t >> 6;
  const int d = t & 63;
  const int ch = blockIdx.x * 4 + w;
  const int slot = blockIdx.y;
  const int dir = dir_base + slot;
  const int b = blockIdx.z;
  const float* rblk = dbc_base + (size_t)slot * SLOT_DBC +
                      ((size_t)b * L_TOT + (size_t)blockIdx.x * 4 * CHUNK) * 20;
#pragma unroll 1
  for (int i = t; i < 4 * CHUNK * 20; i += 256) rpl[i] = rblk[i];
  __syncthreads();
  const float* rp = rpl + w * CHUNK * 20;
  float a[8];
#pragma unroll
  for (int n = 0; n < 8; ++n) a[n] = -__expf(alog[((size_t)dir * 64 + d) * 8 + n]);
  float wdt[4];
#pragma unroll
  for (int r = 0; r < 4; ++r) wdt[r] = dtw[((size_t)dir * 64 + d) * 4 + r];
  const float bia = dtbias[dir * 64 + d];
  const float Dv = dsk[dir * 64 + d];
  const float* up = xd_in + (size_t)slot * SLOT_XD + ((size_t)b * L_TOT + ch * CHUNK) * 64;
  const float* hsp = hcb + (size_t)slot * SLOT_HC + (((size_t)b * NCH + ch) * 64 + d) * 8;
  float h[8];
#pragma unroll
  for (int n = 0; n < 8; ++n) h[n] = hsp[n];
  const int sbase = ch * CHUNK;
#pragma unroll 4
  for (int s = 0; s < CHUNK; ++s) {
    float u = up[s * 64 + d];
    float dt = bia;
#pragma unroll
    for (int r = 0; r < 4; ++r) dt = fmaf(rp[s * 20 + r], wdt[r], dt);
    dt = softplus_f(dt);
    float du = dt * u;
    float y = u * Dv;
#pragma unroll
    for (int n = 0; n < 8; ++n) {
      h[n] = fmaf(__expf(dt * a[n]), h[n], du * rp[s * 20 + 4 + n]);
      y = fmaf(rp[s * 20 + 12 + n], h[n], y);
    }
    if (scatter) {
      int l = tau_map(dir, sbase + s);
      float* yp = y_base + ((size_t)b * L_TOT + l) * 64 + d;
      *yp += y;                      // dirs serialized on the stream in this mode
    } else {
      y_base[(size_t)slot * SLOT_XD + ((size_t)b * L_TOT + sbase + s) * 64 + d] = y;
    }
  }
}

// ---- F: gather + /4 + LN + *silu(z) + out_proj + residual as LDS-tiled GEMM ----
__global__ void __launch_bounds__(256)
k_final(const float* __restrict__ ybase, const float* __restrict__ zbuf,
        const float* __restrict__ ong, const float* __restrict__ onb,
        const float* __restrict__ OW, const float* __restrict__ inp,
        float* __restrict__ out, int gather) {
  __shared__ float xt[64 * 65];        // y tile [l][c] -> normalized -> so[j][65]
  __shared__ float tzw[64 * 65];       // z tile [l][c] -> W[64][65]
  __shared__ float st[640];            // LN stats
  const int t = threadIdx.x;
  const int lane = t & 63;
  const int w = t >> 6;
  const int b = blockIdx.x >> 8;
  const int l0 = (blockIdx.x & 255) << 6;
  // gather + z load (coalesced: lane = channel)
#pragma unroll 2
  for (int rep = 0; rep < 16; ++rep) {
    int r = rep * 4 + w;
    int l = l0 + r;
    float acc;
    if (gather) {
      acc = 0.f;
#pragma unroll
      for (int dir = 0; dir < 4; ++dir) {
        int s = tau_map(dir, l);
        acc += ybase[(size_t)dir * SLOT_XD + ((size_t)b * L_TOT + s) * 64 + lane];
      }
    } else {
      acc = ybase[((size_t)b * L_TOT + l) * 64 + lane];
    }
    xt[r * 65 + lane] = acc * 0.25f;
    tzw[r * 65 + lane] = zbuf[((size_t)b * L_TOT + l) * 64 + lane];
  }
  __syncthreads();
  {  // LN stats
    float s1 = 0.f, s2 = 0.f;
    const int c0 = w * 16;
#pragma unroll
    for (int cc = 0; cc < 16; ++cc) {
      float v = xt[lane * 65 + c0 + cc];
      s1 += v; s2 = fmaf(v, v, s2);
    }
    st[w * 64 + lane] = s1;
    st[256 + w * 64 + lane] = s2;
  }
  __syncthreads();
  if (t < 64) {
    float s1 = st[t] + st[64 + t] + st[128 + t] + st[192 + t];
    float s2 = st[256 + t] + st[320 + t] + st[384 + t] + st[448 + t];
    float m = s1 * 0.015625f;
    float var = s2 * 0.015625f - m * m;
    st[512 + t] = m;
    st[576 + t] = rsqrtf(var + 1e-5f);
  }
  __syncthreads();
  {  // normalize + silu(z) gate, in place
    const float mv = st[512 + lane], rv = st[576 + lane];
#pragma unroll 4
    for (int k = 0; k < 16; ++k) {
      int c = w + 4 * k;
      float g = ong[c], bb = onb[c];
      float v = xt[lane * 65 + c];
      float zz = tzw[lane * 65 + c];
      xt[lane * 65 + c] = ((v - mv) * rv * g + bb) * silu_f(zz);
    }
  }
  __syncthreads();
  // stage OW [64][65] into tzw (z dead)
#pragma unroll 4
  for (int rep = 0; rep < 16; ++rep) {
    int j = rep * 4 + w;
    tzw[j * 65 + lane] = OW[(size_t)j * 64 + lane];
  }
  __syncthreads();
  // GEMM 4x4 register sub-tile
  const int rg = lane & 15;
  const int jg = lane >> 4;
  const int j0 = w * 16 + jg * 4;
  const int r0 = rg * 4;
  float acc[4][4] = {};
#pragma unroll 2
  for (int c = 0; c < 64; ++c) {
    float xv[4], wv[4];
#pragma unroll
    for (int i = 0; i < 4; ++i) xv[i] = xt[(r0 + i) * 65 + c];
#pragma unroll
    for (int jj = 0; jj < 4; ++jj) wv[jj] = tzw[(j0 + jj) * 65 + c];
#pragma unroll
    for (int i = 0; i < 4; ++i)
#pragma unroll
      for (int jj = 0; jj < 4; ++jj) acc[i][jj] = fmaf(xv[i], wv[jj], acc[i][jj]);
  }
  __syncthreads();
  // so[j][r] into xt region
#pragma unroll
  for (int i = 0; i < 4; ++i)
#pragma unroll
    for (int jj = 0; jj < 4; ++jj) xt[(j0 + jj) * 65 + r0 + i] = acc[i][jj];
  __syncthreads();
  // store + residual (coalesced along l)
#pragma unroll 4
  for (int rep = 0; rep < 16; ++rep) {
    int j = rep * 4 + w;
    size_t o = ((size_t)b * 64 + j) * L_TOT + l0 + lane;
    out[o] = xt[j * 65 + lane] + inp[o];
  }
}

extern "C" void kernel_launch(void* const* d_in, const int* in_sizes, int n_in,
                              void* d_out, int out_size, void* d_ws, size_t ws_size,
                              hipStream_t stream) {
  const float* inp    = (const float*)d_in[0];
  const float* lng    = (const float*)d_in[1];
  const float* lnb    = (const float*)d_in[2];
  const float* ipw    = (const float*)d_in[3];
  const float* cw     = (const float*)d_in[4];
  const float* cb     = (const float*)d_in[5];
  const float* xpw    = (const float*)d_in[6];
  const float* dtw    = (const float*)d_in[7];
  const float* dtbias = (const float*)d_in[8];
  const float* alog   = (const float*)d_in[9];
  const float* dsk    = (const float*)d_in[10];
  const float* ong    = (const float*)d_in[11];
  const float* onb    = (const float*)d_in[12];
  const float* opw    = (const float*)d_in[13];
  float* out = (float*)d_out;
  float* ws = (float*)d_ws;

  // batched layout: hc aliases xbuf (dead after convproj); 4*SLOT_HC == SLOT_XD
  const size_t need_batched = (6 * SLOT_XD + 4 * SLOT_DBC + 4 * SLOT_SDT) * sizeof(float);

  if (ws_size >= need_batched) {
    size_t off = 0;
    float* xbuf = ws + off; off += SLOT_XD;          // also hc after convproj
    float* zbuf = ws + off; off += SLOT_XD;
    float* xd   = ws + off; off += 4 * SLOT_XD;
    float* dbc  = ws + off; off += 4 * SLOT_DBC;
    float* sdt  = ws + off; off += 4 * SLOT_SDT;
    float* hc   = xbuf;

    k_ln_inproj<<<dim3(512), 256, 0, stream>>>(inp, lng, lnb, ipw, xbuf, zbuf);
    k_convproj<<<dim3(512, 4), 256, 0, stream>>>(xbuf, cw, cb, xpw, xd, dbc, 0);
    k_scan1<<<dim3(NCH / 4, 4, B_SZ), 256, 0, stream>>>(xd, dbc, alog, dtw, dtbias, hc, sdt, 0);
    k_scan2<<<dim3(512, 4, B_SZ), NCH, 0, stream>>>(hc, sdt, alog, 0);
    k_scan3<<<dim3(NCH / 4, 4, B_SZ), 256, 0, stream>>>(xd, dbc, hc, alog, dtw, dtbias, dsk,
                                                        xd, 0, 0);
    k_final<<<dim3(512), 256, 0, stream>>>(xd, zbuf, ong, onb, opw, inp, out, 1);
  } else {
    size_t off = 0;
    float* xbuf = ws + off; off += SLOT_XD;
    float* zbuf = ws + off; off += SLOT_XD;
    float* ysum = ws + off; off += SLOT_XD;
    float* xd   = ws + off; off += SLOT_XD;
    float* dbc  = ws + off; off += SLOT_DBC;
    float* sdt  = ws + off; off += SLOT_SDT;
    float* hc   = ws + off; off += SLOT_HC;

    hipMemsetAsync(ysum, 0, SLOT_XD * sizeof(float), stream);
    k_ln_inproj<<<dim3(512), 256, 0, stream>>>(inp, lng, lnb, ipw, xbuf, zbuf);
    for (int d2 = 0; d2 < 4; ++d2) {
      k_convproj<<<dim3(512, 1), 256, 0, stream>>>(xbuf, cw, cb, xpw, xd, dbc, d2);
      k_scan1<<<dim3(NCH / 4, 1, B_SZ), 256, 0, stream>>>(xd, dbc, alog, dtw, dtbias, hc, sdt, d2);
      k_scan2<<<dim3(512, 1, B_SZ), NCH, 0, stream>>>(hc, sdt, alog, d2);
      k_scan3<<<dim3(NCH / 4, 1, B_SZ), 256, 0, stream>>>(xd, dbc, hc, alog, dtw, dtbias, dsk,
                                                          ysum, d2, 1);
    }
    k_final<<<dim3(512), 256, 0, stream>>>(ysum, zbuf, ong, onb, opw, inp, out, 0);
  }
}